// Round 9
// baseline (1184.718 us; speedup 1.0000x reference)
//
#include <hip/hip_runtime.h>

typedef unsigned short u16;
typedef unsigned int u32;
typedef __attribute__((ext_vector_type(8))) __bf16 bf16x8;
typedef __attribute__((ext_vector_type(4))) float f32x4;
typedef __attribute__((ext_vector_type(4))) u16 u16x4;

#define VOL 262144  // 64^3
#define TSZ ((size_t)33554432)  // elems per [B,C,64^3] tensor

__device__ __forceinline__ u16 f2bf(float f) {
  u32 u = __builtin_bit_cast(u32, f);
  u32 r = u + 0x7FFFu + ((u >> 16) & 1u);
  return (u16)(r >> 16);
}
__device__ __forceinline__ float bf2f(u16 h) {
  return __builtin_bit_cast(float, ((u32)h) << 16);
}
__device__ __forceinline__ bf16x8 ldsfrag(const u16* p) { return *(const bf16x8*)p; }

// async 16B/lane global->LDS: LDS dest = uniform base + lane*16, global src per-lane.
__device__ __forceinline__ void gload16(const u16* g, u16* l) {
  __builtin_amdgcn_global_load_lds(
      (const __attribute__((address_space(1))) u32*)g,
      (__attribute__((address_space(3))) u32*)l, 16, 0, 0);
}

// pitch-64 XOR swizzle for attn buffers.
__device__ __forceinline__ int swA(int row, int col) {
  return row * 64 + (col ^ (((row ^ (row >> 3)) & 7) << 3));
}

// ---------------- weight pre-swizzle: Wq/Wk/Wv -> per-lane B-fragment order ----------------
__global__ __launch_bounds__(256) void swz_qkv(const float* __restrict__ Wq,
    const float* __restrict__ Wk, const float* __restrict__ Wv, u16* __restrict__ out) {
  int idx = blockIdx.x * 256 + threadIdx.x;
  if (idx >= 54 * 12 * 64 * 8) return;
  int jj = idx & 7;
  int lane = (idx >> 3) & 63;
  int t = idx >> 9;
  int nf = t % 12, s = t / 12;
  int dh = s / 18, sub = s % 18;
  int dw = sub / 6, dd = (sub >> 1) % 3, c32 = sub & 1;
  int coutg = nf * 16 + (lane & 15);
  int cin = c32 * 32 + (lane >> 4) * 8 + jj;
  const float* W = (coutg < 64) ? Wq : ((coutg < 128) ? Wk : Wv);
  int c = coutg & 63;
  out[idx] = f2bf(W[(c * 64 + cin) * 27 + dh * 9 + dw * 3 + dd]);
}

// K order (s in [0,162)): dh(3) / t(3) / dw(3) / dd(3) / c32(2)
__global__ __launch_bounds__(256) void swz_c(const float* __restrict__ Wc, u16* __restrict__ out) {
  int idx = blockIdx.x * 256 + threadIdx.x;
  if (idx >= 162 * 4 * 64 * 8) return;
  int jj = idx & 7;
  int lane = (idx >> 3) & 63;
  int nf = (idx >> 9) & 3;
  int s = idx >> 11;
  int dh = s / 54, rem = s % 54;
  int t = rem / 18, sub = rem % 18;
  int dw = sub / 6, dd = (sub >> 1) % 3, c32 = sub & 1;
  int cout = nf * 16 + (lane & 15);
  int cin = t * 64 + c32 * 32 + (lane >> 4) * 8 + jj;
  out[idx] = f2bf(Wc[(cout * 192 + cin) * 27 + dh * 9 + dw * 3 + dd]);
}

// ---------------- x f32 [B,C,H,W,D] -> bf16 channels-last pre-swizzled pages ----------------
__global__ __launch_bounds__(256, 4) void xcvt(const float* __restrict__ x, u16* __restrict__ xcl) {
  __shared__ __align__(16) u16 tile[4096];
  int id = blockIdx.x;  // (b*64+h)*64 + w
  int b = id >> 12;
  int t = threadIdx.x;
  int c0 = (t & 31) * 2, d0 = (t >> 5) * 8;
  const float* p0 = x + (size_t)(b * 64 + c0) * VOL + (size_t)(id & 4095) * 64 + d0;
  float4 r00 = *(const float4*)p0;
  float4 r01 = *(const float4*)(p0 + 4);
  float4 r10 = *(const float4*)(p0 + VOL);
  float4 r11 = *(const float4*)(p0 + VOL + 4);
  float a0[8] = {r00.x, r00.y, r00.z, r00.w, r01.x, r01.y, r01.z, r01.w};
  float a1[8] = {r10.x, r10.y, r10.z, r10.w, r11.x, r11.y, r11.z, r11.w};
#pragma unroll
  for (int i = 0; i < 8; ++i) {
    int d = d0 + i;
    *(u32*)&tile[d * 64 + (c0 ^ ((d & 7) << 3))] =
        (u32)f2bf(a0[i]) | ((u32)f2bf(a1[i]) << 16);
  }
  __syncthreads();
  u16* dst = xcl + ((size_t)id << 12);
  *(uint4*)&dst[t * 16] = *(const uint4*)&tile[t * 16];
  *(uint4*)&dst[t * 16 + 8] = *(const uint4*)&tile[t * 16 + 8];
}

// ---------------- repackA: avaT [b][c][d][h][w] -> avcl page[(b*64+h)*64+w] = [d][c^((d&7)<<3)] ----------------
__global__ __launch_bounds__(256, 4) void repackA(const u16* __restrict__ src, u16* __restrict__ dst) {
  __shared__ __align__(16) u16 T[64 * 4 * 72];  // [w][dd][72]
  int j = blockIdx.x;
  int b = j >> 10, h = (j >> 4) & 63, d0 = (j & 15) * 4;
  int tid = threadIdx.x;
  int kk = d0 & 4;
#pragma unroll
  for (int k = 0; k < 8; ++k) {
    int chunk = tid + 256 * k;
    int row = chunk >> 3, woct = chunk & 7;
    int c = row >> 2, dd = row & 3;
    uint4 v = *(const uint4*)&src[(size_t)(b * 64 + c) * VOL + (size_t)(d0 + dd) * 4096 +
                                  h * 64 + woct * 8];
    union { uint4 u; u16 s[8]; } U; U.u = v;
    int d7 = kk + dd;
#pragma unroll
    for (int wi = 0; wi < 8; ++wi) {
      T[(woct * 8 + wi) * 288 + dd * 72 + (c ^ ((d7 ^ wi) << 3))] = U.s[wi];
    }
  }
  __syncthreads();
#pragma unroll
  for (int k = 0; k < 8; ++k) {
    int cn = tid + 256 * k;
    int w = cn >> 5, rem = cn & 31;
    int dd = rem >> 3, j8 = rem & 7;
    uint4 v = *(const uint4*)&T[w * 288 + dd * 72 + ((j8 ^ (w & 7)) << 3)];
    *(uint4*)&dst[(size_t)((b * 64 + h) * 64 + w) * 4096 + (d0 + dd) * 64 + j8 * 8] = v;
  }
}

// ---------------- repackB: AV normal [b][c][h][w][d] -> avcl pages ----------------
__global__ __launch_bounds__(256, 4) void repackB(const u16* __restrict__ src, u16* __restrict__ dst) {
  __shared__ __align__(16) u16 T[4 * 64 * 72];  // [wi2][d][72]
  int j = blockIdx.x;
  int b = j >> 10, h = (j >> 4) & 63, w0 = (j & 15) * 4;
  int tid = threadIdx.x;
#pragma unroll
  for (int k = 0; k < 8; ++k) {
    int chunk = tid + 256 * k;
    int row = chunk >> 3, doct = chunk & 7;
    int c = row >> 2, wi2 = row & 3;
    uint4 v = *(const uint4*)&src[(size_t)(b * 64 + c) * VOL + h * 4096 + (w0 + wi2) * 64 +
                                  doct * 8];
    union { uint4 u; u16 s[8]; } U; U.u = v;
#pragma unroll
    for (int di = 0; di < 8; ++di) {
      T[wi2 * 4608 + (doct * 8 + di) * 72 + (c ^ ((di ^ wi2) << 3))] = U.s[di];
    }
  }
  __syncthreads();
#pragma unroll
  for (int k = 0; k < 8; ++k) {
    int cn = tid + 256 * k;
    int wi2 = cn >> 9, rem = cn & 511;
    int d = rem >> 3, j8 = rem & 7;
    uint4 v = *(const uint4*)&T[wi2 * 4608 + d * 72 + ((j8 ^ wi2) << 3)];
    *(uint4*)&dst[(size_t)((b * 64 + h) * 64 + w0 + wi2) * 4096 + d * 64 + j8 * 8] = v;
  }
}

// ---------------- fused q/k/v conv3d (implicit GEMM, BM=128, N=192, 8 waves, gload staging) ----------------
__global__ __launch_bounds__(512, 2) void conv_qkv(const u16* __restrict__ xcl,
    const u16* __restrict__ BQ, const float* __restrict__ bq, const float* __restrict__ bk,
    const float* __restrict__ bv, u16* __restrict__ qb, u16* __restrict__ kb,
    u16* __restrict__ vb) {
  __shared__ __align__(16) u16 xT[2 * 16896];  // 2 buf x 4 tiles x 4224 elems
  int tid = threadIdx.x;
  int id = blockIdx.x;
  int lin = (id & 7) * 512 + (id >> 3);
  int b = lin >> 11, h = (lin >> 5) & 63, w0 = (lin & 31) * 2;
  int wave = tid >> 6, lane = tid & 63, r = lane & 15, g = lane >> 4;
  int mhalf = wave >> 2, nq = wave & 3;
  {
    int tl = tid >> 7, rs = (tid >> 6) & 1, ci = tid & 63;
    int off = tl * 4224 + rs * 65 * 64 + ci;
    xT[off] = 0;
    xT[16896 + off] = 0;
  }
  if (w0 == 0) {
    *(uint4*)&xT[64 + tid * 8] = uint4{0, 0, 0, 0};
    *(uint4*)&xT[16896 + 64 + tid * 8] = uint4{0, 0, 0, 0};
  }
  if (w0 == 62) {
    *(uint4*)&xT[3 * 4224 + 64 + tid * 8] = uint4{0, 0, 0, 0};
    *(uint4*)&xT[16896 + 3 * 4224 + 64 + tid * 8] = uint4{0, 0, 0, 0};
  }
  int tw = wave >> 1, half = wave & 1;
  int wws = w0 + tw - 1;
  bool doload = (unsigned)wws < 64u;

  f32x4 acc[4][3];
#pragma unroll
  for (int i = 0; i < 4; ++i)
#pragma unroll
    for (int j = 0; j < 3; ++j)
#pragma unroll
      for (int e = 0; e < 4; ++e) acc[i][j][e] = 0.0f;

  int dhlo = (h == 0) ? 1 : 0, dhhi = (h == 63) ? 1 : 2;
  if (doload) {
    int hh = h + dhlo - 1;
    const u16* gp = xcl + (((size_t)(b * 64 + hh) * 64 + wws) << 12) + (half << 11) + (lane << 3);
    u16* lp = &xT[tw * 4224 + 64 + half * 2048];
#pragma unroll
    for (int j = 0; j < 4; ++j) gload16(gp + j * 512, lp + j * 512);
  }
  int cur = 0;
  for (int dh = dhlo; dh <= dhhi; ++dh) {
    __syncthreads();
    if (dh < dhhi && doload) {
      int hh = h + dh;
      const u16* gp =
          xcl + (((size_t)(b * 64 + hh) * 64 + wws) << 12) + (half << 11) + (lane << 3);
      u16* lp = &xT[(cur ^ 1) * 16896 + tw * 4224 + 64 + half * 2048];
#pragma unroll
      for (int j = 0; j < 4; ++j) gload16(gp + j * 512, lp + j * 512);
    }
    const u16* Bbase = BQ + ((size_t)(dh * 18) * 12 + nq * 3) * 512 + (size_t)lane * 8;
    int bufE = cur * 16896;
    for (int sub = 0; sub < 18; ++sub) {
      int dw = sub / 6, dd = (sub >> 1) % 3, c32 = sub & 1;
      int colb = c32 * 32 + g * 8;
      int wwi = mhalf + dw;
      bf16x8 A[4];
#pragma unroll
      for (int l = 0; l < 4; ++l) {
        int dpos = l * 16 + r + dd;
        A[l] = ldsfrag(&xT[bufE + wwi * 4224 + dpos * 64 + (colb ^ (((dpos - 1) & 7) << 3))]);
      }
      const u16* Bp = Bbase + (size_t)sub * 12 * 512;
#pragma unroll
      for (int nf = 0; nf < 3; ++nf) {
        bf16x8 Bf = *(const bf16x8*)(Bp + nf * 512);
#pragma unroll
        for (int l = 0; l < 4; ++l)
          acc[l][nf] = __builtin_amdgcn_mfma_f32_16x16x32_bf16(A[l], Bf, acc[l][nf], 0, 0, 0);
      }
    }
    cur ^= 1;
  }
#pragma unroll
  for (int nf = 0; nf < 3; ++nf) {
    int coutg = (nq * 3 + nf) * 16 + r;
    int ten = coutg >> 6, c = coutg & 63;
    u16* dst = (ten == 0) ? qb : ((ten == 1) ? kb : vb);
    const float* bias = (ten == 0) ? bq : ((ten == 1) ? bk : bv);
    float bsv = bias[c];
#pragma unroll
    for (int l = 0; l < 4; ++l) {
      int d0 = l * 16 + g * 4;
      int idx = (b * 64 + c) * VOL + h * 4096 + (w0 + mhalf) * 64 + d0;
      u16x4 o;
#pragma unroll
      for (int jj = 0; jj < 4; ++jj) o[jj] = f2bf(acc[l][nf][jj] + bsv);
      *(u16x4*)(dst + idx) = o;
    }
  }
}

// ---------------- tiled transpose within each (b,c) volume: src[P][Q] -> dst[Q][P] ----------------
__global__ __launch_bounds__(256, 6) void ktranspose(const u16* __restrict__ src,
    u16* __restrict__ dst, int P, int Q) {
  __shared__ __align__(16) u16 tile[64 * 72];
  int tid = threadIdx.x;
  int id = blockIdx.x;
  int bc = id >> 6, t = id & 63;
  int qt = Q >> 6;
  int p0 = (t / qt) * 64, q0 = (t % qt) * 64;
  const u16* s = src + (size_t)bc * VOL;
  u16* d = dst + (size_t)bc * VOL;
#pragma unroll
  for (int it = 0; it < 2; ++it) {
    int c = tid + 256 * it;
    int i2 = c >> 3, sg = c & 7;
    *(uint4*)&tile[i2 * 72 + ((sg * 8) ^ (((i2 >> 3) & 7) << 3))] =
        *(const uint4*)&s[(size_t)(p0 + i2) * Q + q0 + sg * 8];
  }
  __syncthreads();
  int j = tid >> 2, ms = tid & 3;
  u16 vals[16];
#pragma unroll
  for (int ii = 0; ii < 16; ++ii) {
    int row = ms * 16 + ii;
    vals[ii] = tile[row * 72 + (j ^ (((row >> 3) & 7) << 3))];
  }
  uint4 o0, o1;
  o0.x = (u32)vals[0] | ((u32)vals[1] << 16);
  o0.y = (u32)vals[2] | ((u32)vals[3] << 16);
  o0.z = (u32)vals[4] | ((u32)vals[5] << 16);
  o0.w = (u32)vals[6] | ((u32)vals[7] << 16);
  o1.x = (u32)vals[8] | ((u32)vals[9] << 16);
  o1.y = (u32)vals[10] | ((u32)vals[11] << 16);
  o1.z = (u32)vals[12] | ((u32)vals[13] << 16);
  o1.w = (u32)vals[14] | ((u32)vals[15] << 16);
  size_t drow = (size_t)(q0 + j) * P + p0 + ms * 16;
  *(uint4*)&d[drow] = o0;
  *(uint4*)&d[drow + 8] = o1;
}

// ---------------- axial attention pass-pair on 64x64 slabs ----------------
__global__ __launch_bounds__(256, 2) void attn_pair(const u16* __restrict__ q,
    const u16* __restrict__ k, const u16* __restrict__ v, u16* __restrict__ dst,
    int uStride, int sMul) {
  __shared__ __align__(16) u16 sm[6 * 4096];
  u16* LQ = sm;             u16* LK = sm + 4096;      u16* LV = sm + 2 * 4096;
  u16* LQT = sm + 3 * 4096; u16* LKT = sm + 4 * 4096; u16* LVT = sm + 5 * 4096;
  u16* A1 = LK;
  u16* A2 = LKT;
  int tid = threadIdx.x;
  int id = blockIdx.x;
  int bc = id >> 6, sidx = id & 63;
  size_t base = (size_t)bc * VOL + (size_t)sidx * sMul;
  int wave = tid >> 6, lane = tid & 63, r = lane & 15, g = lane >> 4;
  int pairid = tid >> 3, seg = tid & 7;
  int u0 = pairid * 2;
  const u16* srcs[3] = {q, k, v};
  u16* Ln_[3] = {LQ, LK, LV};
  u16* Lt_[3] = {LQT, LKT, LVT};
#pragma unroll
  for (int t3 = 0; t3 < 3; ++t3) {
    const u16* p = srcs[t3] + base + (size_t)u0 * uStride + seg * 8;
    uint4 ra = *(const uint4*)p;
    uint4 rb = *(const uint4*)(p + uStride);
    *(uint4*)&Ln_[t3][swA(u0, seg * 8)] = ra;
    *(uint4*)&Ln_[t3][swA(u0 + 1, seg * 8)] = rb;
    union { uint4 vv; u16 ss[8]; } Ua, Ub;
    Ua.vv = ra; Ub.vv = rb;
#pragma unroll
    for (int vi = 0; vi < 8; ++vi) {
      int vvx = seg * 8 + vi;
      *(u32*)&Lt_[t3][swA(vvx, u0)] = (u32)Ua.ss[vi] | ((u32)Ub.ss[vi] << 16);
    }
  }
  __syncthreads();
  int row0 = wave * 16;
  f32x4 s1[4], s2[4];
#pragma unroll
  for (int nf = 0; nf < 4; ++nf)
#pragma unroll
    for (int e = 0; e < 4; ++e) { s1[nf][e] = 0.f; s2[nf][e] = 0.f; }
#pragma unroll
  for (int ks = 0; ks < 2; ++ks) {
    int cb = ks * 32 + g * 8;
    bf16x8 aK = ldsfrag(&LK[swA(row0 + r, cb)]);
    bf16x8 aKT = ldsfrag(&LKT[swA(row0 + r, cb)]);
#pragma unroll
    for (int nf = 0; nf < 4; ++nf) {
      bf16x8 bQ = ldsfrag(&LQ[swA(nf * 16 + r, cb)]);
      bf16x8 bQT = ldsfrag(&LQT[swA(nf * 16 + r, cb)]);
      s1[nf] = __builtin_amdgcn_mfma_f32_16x16x32_bf16(aK, bQ, s1[nf], 0, 0, 0);
      s2[nf] = __builtin_amdgcn_mfma_f32_16x16x32_bf16(aKT, bQT, s2[nf], 0, 0, 0);
    }
  }
  __syncthreads();
#pragma unroll
  for (int m2 = 0; m2 < 2; ++m2) {
    f32x4* ss = m2 ? s2 : s1;
    u16* Adst = m2 ? A2 : A1;
#pragma unroll
    for (int jj = 0; jj < 4; ++jj) {
      float mx = fmaxf(fmaxf(ss[0][jj], ss[1][jj]), fmaxf(ss[2][jj], ss[3][jj]));
      mx = fmaxf(mx, __shfl_xor(mx, 1, 64));
      mx = fmaxf(mx, __shfl_xor(mx, 2, 64));
      mx = fmaxf(mx, __shfl_xor(mx, 4, 64));
      mx = fmaxf(mx, __shfl_xor(mx, 8, 64));
      float p0 = __expf((ss[0][jj] - mx) * 0.125f);
      float p1 = __expf((ss[1][jj] - mx) * 0.125f);
      float p2 = __expf((ss[2][jj] - mx) * 0.125f);
      float p3 = __expf((ss[3][jj] - mx) * 0.125f);
      float sum = p0 + p1 + p2 + p3;
      sum += __shfl_xor(sum, 1, 64);
      sum += __shfl_xor(sum, 2, 64);
      sum += __shfl_xor(sum, 4, 64);
      sum += __shfl_xor(sum, 8, 64);
      float inv = 1.0f / sum;
      ss[0][jj] = p0 * inv; ss[1][jj] = p1 * inv; ss[2][jj] = p2 * inv; ss[3][jj] = p3 * inv;
    }
    int j0 = row0 + g * 4;
#pragma unroll
    for (int nf = 0; nf < 4; ++nf) {
      int i = nf * 16 + r;
      int a0 = swA(i, j0);
      *(u32*)&Adst[a0]     = (u32)f2bf(ss[nf][0]) | ((u32)f2bf(ss[nf][1]) << 16);
      *(u32*)&Adst[a0 + 2] = (u32)f2bf(ss[nf][2]) | ((u32)f2bf(ss[nf][3]) << 16);
    }
  }
  __syncthreads();
  f32x4 o[4];
#pragma unroll
  for (int nf = 0; nf < 4; ++nf)
#pragma unroll
    for (int e = 0; e < 4; ++e) o[nf][e] = 0.f;
#pragma unroll
  for (int ks = 0; ks < 2; ++ks) {
    int cb = ks * 32 + g * 8;
    bf16x8 aA = ldsfrag(&A1[swA(row0 + r, cb)]);
    bf16x8 aV = ldsfrag(&LV[swA(row0 + r, cb)]);
#pragma unroll
    for (int nf = 0; nf < 4; ++nf) {
      bf16x8 bVT = ldsfrag(&LVT[swA(nf * 16 + r, cb)]);
      bf16x8 bA2 = ldsfrag(&A2[swA(nf * 16 + r, cb)]);
      o[nf] = __builtin_amdgcn_mfma_f32_16x16x32_bf16(aA, bVT, o[nf], 0, 0, 0);
      o[nf] = __builtin_amdgcn_mfma_f32_16x16x32_bf16(aV, bA2, o[nf], 0, 0, 0);
    }
  }
#pragma unroll
  for (int nf = 0; nf < 4; ++nf) {
    int vv = nf * 16 + r;
#pragma unroll
    for (int jj = 0; jj < 4; ++jj) {
      int u = row0 + g * 4 + jj;
      dst[base + (size_t)u * uStride + vv] = f2bf(o[nf][jj] * 0.5f);
    }
  }
}

// ---------------- final conv3d from avcl pages, double-buffered gload pipeline ----------------
// 2 x 50.7KB LDS (1 block/CU, 8 waves). One barrier per (dh,t) phase: the swap barrier
// drains the PREVIOUS phase's prefetch (issued a full 18-sub compute earlier).
__global__ __launch_bounds__(512, 2) void conv_final(const u16* __restrict__ avcl,
    const u16* __restrict__ BCw, const float* __restrict__ bcb,
    const u16* __restrict__ qb, float* __restrict__ out) {
  __shared__ __align__(16) u16 xT[2 * 25344];  // 2 buf x 6 tiles x 4224
  int tid = threadIdx.x;
  int id = blockIdx.x;
  int lin = (id & 7) * 256 + (id >> 3);  // 2048 = 8*256
  int b = lin >> 10, h = (lin >> 4) & 63, w0 = (lin & 15) * 4;
  int wave = tid >> 6, lane = tid & 63, r = lane & 15, g = lane >> 4;
  int mw = wave >> 1, nw = wave & 1;
  for (int z = tid; z < 1536; z += 512) {  // zero pad rows (dpos 0, 65) of 12 tiles
    int tl = z >> 7, rs = (z >> 6) & 1, ci = z & 63;
    xT[tl * 4224 + rs * 65 * 64 + ci] = 0;
  }
  if (w0 == 0) {  // OOB tile 0 in both buffers
    *(uint4*)&xT[64 + tid * 8] = uint4{0, 0, 0, 0};
    *(uint4*)&xT[25344 + 64 + tid * 8] = uint4{0, 0, 0, 0};
  }
  if (w0 == 60) {  // OOB tile 5 in both buffers
    *(uint4*)&xT[5 * 4224 + 64 + tid * 8] = uint4{0, 0, 0, 0};
    *(uint4*)&xT[25344 + 5 * 4224 + 64 + tid * 8] = uint4{0, 0, 0, 0};
  }
  int tw1 = wave >> 1, hf1 = wave & 1;        // staging unit 1: tiles 0..3 (8 waves)
  int tw2 = 4 + (wave >> 1), hf2 = wave & 1;  // staging unit 2: tiles 4,5 (waves 0..3)
  int ww1 = w0 + tw1 - 1, ww2 = w0 + tw2 - 1;
  bool dl1 = (unsigned)ww1 < 64u;
  bool dl2 = (wave < 4) && ((unsigned)ww2 < 64u);

  f32x4 acc[4][2];
#pragma unroll
  for (int i = 0; i < 4; ++i)
#pragma unroll
    for (int j = 0; j < 2; ++j)
#pragma unroll
      for (int e = 0; e < 4; ++e) acc[i][j][e] = 0.f;

  int dhlo = (h == 0) ? 1 : 0, dhhi = (h == 63) ? 1 : 2;
  int np = (dhhi - dhlo + 1) * 3;

  auto stage = [&](int bufE, int dh, int t) {
    int hh = h + dh - 1;
    const u16* tbase = avcl + (size_t)t * TSZ;
    if (dl1) {
      const u16* gp = tbase + (((size_t)(b * 64 + hh) * 64 + ww1) << 12) + (hf1 << 11) + (lane << 3);
      u16* lp = &xT[bufE + tw1 * 4224 + 64 + hf1 * 2048];
#pragma unroll
      for (int j = 0; j < 4; ++j) gload16(gp + j * 512, lp + j * 512);
    }
    if (dl2) {
      const u16* gp = tbase + (((size_t)(b * 64 + hh) * 64 + ww2) << 12) + (hf2 << 11) + (lane << 3);
      u16* lp = &xT[bufE + tw2 * 4224 + 64 + hf2 * 2048];
#pragma unroll
      for (int j = 0; j < 4; ++j) gload16(gp + j * 512, lp + j * 512);
    }
  };

  stage(0, dhlo, 0);  // prologue
  int cur = 0;
  for (int p = 0; p < np; ++p) {
    __syncthreads();  // buf[cur] loads complete (issued one full phase ago); prev compute done
    if (p + 1 < np) {
      int pn = p + 1;
      stage((cur ^ 1) * 25344, dhlo + pn / 3, pn % 3);  // issue next; lands during compute
    }
    int dh = dhlo + p / 3, t = p % 3;
    const u16* Bbase = BCw + ((size_t)((dh * 3 + t) * 18) * 4 + nw * 2) * 512 + (size_t)lane * 8;
    int bufE = cur * 25344;
    for (int sub = 0; sub < 18; ++sub) {
      int dw = sub / 6, dd = (sub >> 1) % 3, c32 = sub & 1;
      int colb = c32 * 32 + g * 8;
      int wwi = mw + dw;
      bf16x8 A[4];
#pragma unroll
      for (int dq = 0; dq < 4; ++dq) {
        int dpos = dq * 16 + r + dd;
        A[dq] = ldsfrag(&xT[bufE + wwi * 4224 + dpos * 64 + (colb ^ (((dpos - 1) & 7) << 3))]);
      }
      const u16* Bp = Bbase + (size_t)sub * 4 * 512;
#pragma unroll
      for (int nf = 0; nf < 2; ++nf) {
        bf16x8 Bf = *(const bf16x8*)(Bp + nf * 512);
#pragma unroll
        for (int dq = 0; dq < 4; ++dq)
          acc[dq][nf] = __builtin_amdgcn_mfma_f32_16x16x32_bf16(A[dq], Bf, acc[dq][nf], 0, 0, 0);
      }
    }
    cur ^= 1;
  }
  const float S = 0.9999950000374997f;  // 1/sqrt(1+1e-5)
#pragma unroll
  for (int nf = 0; nf < 2; ++nf) {
    int cout = (nw * 2 + nf) * 16 + r;
    float bsv = bcb[cout];
#pragma unroll
    for (int dq = 0; dq < 4; ++dq) {
      int d0 = dq * 16 + g * 4;
      int idx = (b * 64 + cout) * VOL + h * 4096 + (w0 + mw) * 64 + d0;
      u16x4 qv = *(const u16x4*)(qb + idx);
      float4 ov;
      float t0 = (acc[dq][nf][0] + bsv) * S; t0 = t0 > 0.f ? t0 : 0.f; ov.x = t0 * S + bf2f(qv[0]);
      float t1 = (acc[dq][nf][1] + bsv) * S; t1 = t1 > 0.f ? t1 : 0.f; ov.y = t1 * S + bf2f(qv[1]);
      float t2 = (acc[dq][nf][2] + bsv) * S; t2 = t2 > 0.f ? t2 : 0.f; ov.z = t2 * S + bf2f(qv[2]);
      float t3 = (acc[dq][nf][3] + bsv) * S; t3 = t3 > 0.f ? t3 : 0.f; ov.w = t3 * S + bf2f(qv[3]);
      *(float4*)(out + idx) = ov;
    }
  }
}

extern "C" void kernel_launch(void* const* d_in, const int* in_sizes, int n_in,
                              void* d_out, int out_size, void* d_ws, size_t ws_size,
                              hipStream_t stream) {
  const float* x  = (const float*)d_in[0];
  const float* Wq = (const float*)d_in[1];
  const float* bq = (const float*)d_in[2];
  const float* Wk = (const float*)d_in[3];
  const float* bk = (const float*)d_in[4];
  const float* Wv = (const float*)d_in[5];
  const float* bv = (const float*)d_in[6];
  const float* Wc = (const float*)d_in[7];
  const float* bc = (const float*)d_in[8];
  float* out = (float*)d_out;
  u16* ws = (u16*)d_ws;
  u16* qb = ws;
  u16* kb = ws + TSZ;
  u16* vb = ws + 2 * TSZ;
  u16* qT = ws + 3 * TSZ;    // after attn1: avcl[0]
  u16* kT = ws + 4 * TSZ;    // after attn1: avcl[1]
  u16* vT = ws + 5 * TSZ;    // after attn1: avcl[2]
  u16* X  = ws + 6 * TSZ;    // scratch: xcl -> avaT -> AVb -> AVc
  u16* BQ = ws + 7 * TSZ;
  u16* BC = BQ + 331776;
  u16* avcl = qT;

  swz_qkv<<<1296, 256, 0, stream>>>(Wq, Wk, Wv, BQ);
  swz_c<<<1296, 256, 0, stream>>>(Wc, BC);
  xcvt<<<8192, 256, 0, stream>>>(x, X);
  conv_qkv<<<4096, 512, 0, stream>>>(X, BQ, bq, bk, bv, qb, kb, vb);
  ktranspose<<<8192, 256, 0, stream>>>(qb, qT, 4096, 64);
  ktranspose<<<8192, 256, 0, stream>>>(kb, kT, 4096, 64);
  ktranspose<<<8192, 256, 0, stream>>>(vb, vT, 4096, 64);
  attn_pair<<<8192, 256, 0, stream>>>(qT, kT, vT, X, 64, 4096);
  repackA<<<2048, 256, 0, stream>>>(X, avcl);
  attn_pair<<<8192, 256, 0, stream>>>(qb, kb, vb, X, 4096, 64);
  repackB<<<2048, 256, 0, stream>>>(X, avcl + TSZ);
  attn_pair<<<8192, 256, 0, stream>>>(qb, kb, vb, X, 64, 4096);
  repackB<<<2048, 256, 0, stream>>>(X, avcl + 2 * TSZ);
  conv_final<<<2048, 512, 0, stream>>>(avcl, BC, bc, qb, out);
}

// Round 10
// 1114.311 us; speedup vs baseline: 1.0632x; 1.0632x over previous
//
#include <hip/hip_runtime.h>

typedef unsigned short u16;
typedef unsigned int u32;
typedef __attribute__((ext_vector_type(8))) __bf16 bf16x8;
typedef __attribute__((ext_vector_type(4))) float f32x4;
typedef __attribute__((ext_vector_type(4))) u16 u16x4;

#define VOL 262144  // 64^3

__device__ __forceinline__ u16 f2bf(float f) {
  u32 u = __builtin_bit_cast(u32, f);
  u32 r = u + 0x7FFFu + ((u >> 16) & 1u);
  return (u16)(r >> 16);
}
__device__ __forceinline__ float bf2f(u16 h) {
  return __builtin_bit_cast(float, ((u32)h) << 16);
}
__device__ __forceinline__ bf16x8 ldsfrag(const u16* p) { return *(const bf16x8*)p; }

// async 16B/lane global->LDS: LDS dest = uniform base + lane*16, global src per-lane.
__device__ __forceinline__ void gload16(const u16* g, u16* l) {
  __builtin_amdgcn_global_load_lds(
      (const __attribute__((address_space(1))) u32*)g,
      (__attribute__((address_space(3))) u32*)l, 16, 0, 0);
}

// pitch-64 XOR swizzle for attn buffers.
__device__ __forceinline__ int swA(int row, int col) {
  return row * 64 + (col ^ (((row ^ (row >> 3)) & 7) << 3));
}

// ---------------- weight pre-swizzle: Wq/Wk/Wv -> per-lane B-fragment order ----------------
// K order (s in [0,54)): dh(3) / dw(3) / dd(3) / c32(2).  nf in [0,12): cout group of 16.
__global__ __launch_bounds__(256) void swz_qkv(const float* __restrict__ Wq,
    const float* __restrict__ Wk, const float* __restrict__ Wv, u16* __restrict__ out) {
  int idx = blockIdx.x * 256 + threadIdx.x;
  if (idx >= 54 * 12 * 64 * 8) return;
  int jj = idx & 7;
  int lane = (idx >> 3) & 63;
  int t = idx >> 9;
  int nf = t % 12, s = t / 12;
  int dh = s / 18, sub = s % 18;
  int dw = sub / 6, dd = (sub >> 1) % 3, c32 = sub & 1;
  int coutg = nf * 16 + (lane & 15);
  int cin = c32 * 32 + (lane >> 4) * 8 + jj;
  const float* W = (coutg < 64) ? Wq : ((coutg < 128) ? Wk : Wv);
  int c = coutg & 63;
  out[idx] = f2bf(W[(c * 64 + cin) * 27 + dh * 9 + dw * 3 + dd]);
}

// K order (s in [0,162)): dh(3) / t(3: AVa,AVb,AVc 64-ch block) / dw(3) / dd(3) / c32(2)
__global__ __launch_bounds__(256) void swz_c(const float* __restrict__ Wc, u16* __restrict__ out) {
  int idx = blockIdx.x * 256 + threadIdx.x;
  if (idx >= 162 * 4 * 64 * 8) return;
  int jj = idx & 7;
  int lane = (idx >> 3) & 63;
  int nf = (idx >> 9) & 3;
  int s = idx >> 11;
  int dh = s / 54, rem = s % 54;
  int t = rem / 18, sub = rem % 18;
  int dw = sub / 6, dd = (sub >> 1) % 3, c32 = sub & 1;
  int cout = nf * 16 + (lane & 15);
  int cin = t * 64 + c32 * 32 + (lane >> 4) * 8 + jj;
  out[idx] = f2bf(Wc[(cout * 192 + cin) * 27 + dh * 9 + dw * 3 + dd]);
}

// ---------------- x f32 [B,C,H,W,D] -> bf16 channels-last pre-swizzled [B,H,W][d][c^((d&7)<<3)] ----------------
__global__ __launch_bounds__(256, 4) void xcvt(const float* __restrict__ x, u16* __restrict__ xcl) {
  __shared__ __align__(16) u16 tile[4096];
  int id = blockIdx.x;  // (b*64+h)*64 + w
  int b = id >> 12;
  int t = threadIdx.x;
  int c0 = (t & 31) * 2, d0 = (t >> 5) * 8;
  const float* p0 = x + (size_t)(b * 64 + c0) * VOL + (size_t)(id & 4095) * 64 + d0;
  float4 r00 = *(const float4*)p0;
  float4 r01 = *(const float4*)(p0 + 4);
  float4 r10 = *(const float4*)(p0 + VOL);
  float4 r11 = *(const float4*)(p0 + VOL + 4);
  float a0[8] = {r00.x, r00.y, r00.z, r00.w, r01.x, r01.y, r01.z, r01.w};
  float a1[8] = {r10.x, r10.y, r10.z, r10.w, r11.x, r11.y, r11.z, r11.w};
#pragma unroll
  for (int i = 0; i < 8; ++i) {
    int d = d0 + i;
    *(u32*)&tile[d * 64 + (c0 ^ ((d & 7) << 3))] =
        (u32)f2bf(a0[i]) | ((u32)f2bf(a1[i]) << 16);
  }
  __syncthreads();
  u16* dst = xcl + ((size_t)id << 12);
  *(uint4*)&dst[t * 16] = *(const uint4*)&tile[t * 16];
  *(uint4*)&dst[t * 16 + 8] = *(const uint4*)&tile[t * 16 + 8];
}

// ---------------- fused q/k/v conv3d (implicit GEMM, BM=128, N=192, 8 waves, gload staging) ----------------
__global__ __launch_bounds__(512, 2) void conv_qkv(const u16* __restrict__ xcl,
    const u16* __restrict__ BQ, const float* __restrict__ bq, const float* __restrict__ bk,
    const float* __restrict__ bv, u16* __restrict__ qb, u16* __restrict__ kb,
    u16* __restrict__ vb) {
  __shared__ __align__(16) u16 xT[2 * 16896];  // 2 buf x 4 tiles x 4224 elems
  int tid = threadIdx.x;
  int id = blockIdx.x;
  int lin = (id & 7) * 512 + (id >> 3);
  int b = lin >> 11, h = (lin >> 5) & 63, w0 = (lin & 31) * 2;
  int wave = tid >> 6, lane = tid & 63, r = lane & 15, g = lane >> 4;
  int mhalf = wave >> 2, nq = wave & 3;
  {
    int tl = tid >> 7, rs = (tid >> 6) & 1, ci = tid & 63;
    int off = tl * 4224 + rs * 65 * 64 + ci;
    xT[off] = 0;
    xT[16896 + off] = 0;
  }
  if (w0 == 0) {
    *(uint4*)&xT[64 + tid * 8] = uint4{0, 0, 0, 0};
    *(uint4*)&xT[16896 + 64 + tid * 8] = uint4{0, 0, 0, 0};
  }
  if (w0 == 62) {
    *(uint4*)&xT[3 * 4224 + 64 + tid * 8] = uint4{0, 0, 0, 0};
    *(uint4*)&xT[16896 + 3 * 4224 + 64 + tid * 8] = uint4{0, 0, 0, 0};
  }
  int tw = wave >> 1, half = wave & 1;
  int wws = w0 + tw - 1;
  bool doload = (unsigned)wws < 64u;

  f32x4 acc[4][3];
#pragma unroll
  for (int i = 0; i < 4; ++i)
#pragma unroll
    for (int j = 0; j < 3; ++j)
#pragma unroll
      for (int e = 0; e < 4; ++e) acc[i][j][e] = 0.0f;

  int dhlo = (h == 0) ? 1 : 0, dhhi = (h == 63) ? 1 : 2;
  if (doload) {
    int hh = h + dhlo - 1;
    const u16* gp = xcl + (((size_t)(b * 64 + hh) * 64 + wws) << 12) + (half << 11) + (lane << 3);
    u16* lp = &xT[tw * 4224 + 64 + half * 2048];
#pragma unroll
    for (int j = 0; j < 4; ++j) gload16(gp + j * 512, lp + j * 512);
  }
  int cur = 0;
  for (int dh = dhlo; dh <= dhhi; ++dh) {
    __syncthreads();
    if (dh < dhhi && doload) {
      int hh = h + dh;
      const u16* gp =
          xcl + (((size_t)(b * 64 + hh) * 64 + wws) << 12) + (half << 11) + (lane << 3);
      u16* lp = &xT[(cur ^ 1) * 16896 + tw * 4224 + 64 + half * 2048];
#pragma unroll
      for (int j = 0; j < 4; ++j) gload16(gp + j * 512, lp + j * 512);
    }
    const u16* Bbase = BQ + ((size_t)(dh * 18) * 12 + nq * 3) * 512 + (size_t)lane * 8;
    int bufE = cur * 16896;
    for (int sub = 0; sub < 18; ++sub) {
      int dw = sub / 6, dd = (sub >> 1) % 3, c32 = sub & 1;
      int colb = c32 * 32 + g * 8;
      int wwi = mhalf + dw;
      bf16x8 A[4];
#pragma unroll
      for (int l = 0; l < 4; ++l) {
        int dpos = l * 16 + r + dd;
        A[l] = ldsfrag(&xT[bufE + wwi * 4224 + dpos * 64 + (colb ^ (((dpos - 1) & 7) << 3))]);
      }
      const u16* Bp = Bbase + (size_t)sub * 12 * 512;
#pragma unroll
      for (int nf = 0; nf < 3; ++nf) {
        bf16x8 Bf = *(const bf16x8*)(Bp + nf * 512);
#pragma unroll
        for (int l = 0; l < 4; ++l)
          acc[l][nf] = __builtin_amdgcn_mfma_f32_16x16x32_bf16(A[l], Bf, acc[l][nf], 0, 0, 0);
      }
    }
    cur ^= 1;
  }
#pragma unroll
  for (int nf = 0; nf < 3; ++nf) {
    int coutg = (nq * 3 + nf) * 16 + r;
    int ten = coutg >> 6, c = coutg & 63;
    u16* dst = (ten == 0) ? qb : ((ten == 1) ? kb : vb);
    const float* bias = (ten == 0) ? bq : ((ten == 1) ? bk : bv);
    float bsv = bias[c];
#pragma unroll
    for (int l = 0; l < 4; ++l) {
      int d0 = l * 16 + g * 4;
      int idx = (b * 64 + c) * VOL + h * 4096 + (w0 + mhalf) * 64 + d0;
      u16x4 o;
#pragma unroll
      for (int jj = 0; jj < 4; ++jj) o[jj] = f2bf(acc[l][nf][jj] + bsv);
      *(u16x4*)(dst + idx) = o;
    }
  }
}

// ---------------- tiled transpose within each (b,c) volume: src[P][Q] -> dst[Q][P] ----------------
__global__ __launch_bounds__(256, 6) void ktranspose(const u16* __restrict__ src,
    u16* __restrict__ dst, int P, int Q) {
  __shared__ __align__(16) u16 tile[64 * 72];
  int tid = threadIdx.x;
  int id = blockIdx.x;
  int bc = id >> 6, t = id & 63;
  int qt = Q >> 6;
  int p0 = (t / qt) * 64, q0 = (t % qt) * 64;
  const u16* s = src + (size_t)bc * VOL;
  u16* d = dst + (size_t)bc * VOL;
#pragma unroll
  for (int it = 0; it < 2; ++it) {
    int c = tid + 256 * it;
    int i2 = c >> 3, sg = c & 7;
    *(uint4*)&tile[i2 * 72 + ((sg * 8) ^ (((i2 >> 3) & 7) << 3))] =
        *(const uint4*)&s[(size_t)(p0 + i2) * Q + q0 + sg * 8];
  }
  __syncthreads();
  int j = tid >> 2, ms = tid & 3;
  u16 vals[16];
#pragma unroll
  for (int ii = 0; ii < 16; ++ii) {
    int row = ms * 16 + ii;
    vals[ii] = tile[row * 72 + (j ^ (((row >> 3) & 7) << 3))];
  }
  uint4 o0, o1;
  o0.x = (u32)vals[0] | ((u32)vals[1] << 16);
  o0.y = (u32)vals[2] | ((u32)vals[3] << 16);
  o0.z = (u32)vals[4] | ((u32)vals[5] << 16);
  o0.w = (u32)vals[6] | ((u32)vals[7] << 16);
  o1.x = (u32)vals[8] | ((u32)vals[9] << 16);
  o1.y = (u32)vals[10] | ((u32)vals[11] << 16);
  o1.z = (u32)vals[12] | ((u32)vals[13] << 16);
  o1.w = (u32)vals[14] | ((u32)vals[15] << 16);
  size_t drow = (size_t)(q0 + j) * P + p0 + ms * 16;
  *(uint4*)&d[drow] = o0;
  *(uint4*)&d[drow + 8] = o1;
}

// ---------------- axial attention pass-pair on 64x64 slabs ----------------
__global__ __launch_bounds__(256, 2) void attn_pair(const u16* __restrict__ q,
    const u16* __restrict__ k, const u16* __restrict__ v, u16* __restrict__ dst,
    int uStride, int sMul) {
  __shared__ __align__(16) u16 sm[6 * 4096];
  u16* LQ = sm;             u16* LK = sm + 4096;      u16* LV = sm + 2 * 4096;
  u16* LQT = sm + 3 * 4096; u16* LKT = sm + 4 * 4096; u16* LVT = sm + 5 * 4096;
  u16* A1 = LK;
  u16* A2 = LKT;
  int tid = threadIdx.x;
  int id = blockIdx.x;
  int bc = id >> 6, sidx = id & 63;
  size_t base = (size_t)bc * VOL + (size_t)sidx * sMul;
  int wave = tid >> 6, lane = tid & 63, r = lane & 15, g = lane >> 4;
  int pairid = tid >> 3, seg = tid & 7;
  int u0 = pairid * 2;
  const u16* srcs[3] = {q, k, v};
  u16* Ln_[3] = {LQ, LK, LV};
  u16* Lt_[3] = {LQT, LKT, LVT};
#pragma unroll
  for (int t3 = 0; t3 < 3; ++t3) {
    const u16* p = srcs[t3] + base + (size_t)u0 * uStride + seg * 8;
    uint4 ra = *(const uint4*)p;
    uint4 rb = *(const uint4*)(p + uStride);
    *(uint4*)&Ln_[t3][swA(u0, seg * 8)] = ra;
    *(uint4*)&Ln_[t3][swA(u0 + 1, seg * 8)] = rb;
    union { uint4 vv; u16 ss[8]; } Ua, Ub;
    Ua.vv = ra; Ub.vv = rb;
#pragma unroll
    for (int vi = 0; vi < 8; ++vi) {
      int vvx = seg * 8 + vi;
      *(u32*)&Lt_[t3][swA(vvx, u0)] = (u32)Ua.ss[vi] | ((u32)Ub.ss[vi] << 16);
    }
  }
  __syncthreads();
  int row0 = wave * 16;
  f32x4 s1[4], s2[4];
#pragma unroll
  for (int nf = 0; nf < 4; ++nf)
#pragma unroll
    for (int e = 0; e < 4; ++e) { s1[nf][e] = 0.f; s2[nf][e] = 0.f; }
#pragma unroll
  for (int ks = 0; ks < 2; ++ks) {
    int cb = ks * 32 + g * 8;
    bf16x8 aK = ldsfrag(&LK[swA(row0 + r, cb)]);
    bf16x8 aKT = ldsfrag(&LKT[swA(row0 + r, cb)]);
#pragma unroll
    for (int nf = 0; nf < 4; ++nf) {
      bf16x8 bQ = ldsfrag(&LQ[swA(nf * 16 + r, cb)]);
      bf16x8 bQT = ldsfrag(&LQT[swA(nf * 16 + r, cb)]);
      s1[nf] = __builtin_amdgcn_mfma_f32_16x16x32_bf16(aK, bQ, s1[nf], 0, 0, 0);
      s2[nf] = __builtin_amdgcn_mfma_f32_16x16x32_bf16(aKT, bQT, s2[nf], 0, 0, 0);
    }
  }
  __syncthreads();
#pragma unroll
  for (int m2 = 0; m2 < 2; ++m2) {
    f32x4* ss = m2 ? s2 : s1;
    u16* Adst = m2 ? A2 : A1;
#pragma unroll
    for (int jj = 0; jj < 4; ++jj) {
      float mx = fmaxf(fmaxf(ss[0][jj], ss[1][jj]), fmaxf(ss[2][jj], ss[3][jj]));
      mx = fmaxf(mx, __shfl_xor(mx, 1, 64));
      mx = fmaxf(mx, __shfl_xor(mx, 2, 64));
      mx = fmaxf(mx, __shfl_xor(mx, 4, 64));
      mx = fmaxf(mx, __shfl_xor(mx, 8, 64));
      float p0 = __expf((ss[0][jj] - mx) * 0.125f);
      float p1 = __expf((ss[1][jj] - mx) * 0.125f);
      float p2 = __expf((ss[2][jj] - mx) * 0.125f);
      float p3 = __expf((ss[3][jj] - mx) * 0.125f);
      float sum = p0 + p1 + p2 + p3;
      sum += __shfl_xor(sum, 1, 64);
      sum += __shfl_xor(sum, 2, 64);
      sum += __shfl_xor(sum, 4, 64);
      sum += __shfl_xor(sum, 8, 64);
      float inv = 1.0f / sum;
      ss[0][jj] = p0 * inv; ss[1][jj] = p1 * inv; ss[2][jj] = p2 * inv; ss[3][jj] = p3 * inv;
    }
    int j0 = row0 + g * 4;
#pragma unroll
    for (int nf = 0; nf < 4; ++nf) {
      int i = nf * 16 + r;
      int a0 = swA(i, j0);
      *(u32*)&Adst[a0]     = (u32)f2bf(ss[nf][0]) | ((u32)f2bf(ss[nf][1]) << 16);
      *(u32*)&Adst[a0 + 2] = (u32)f2bf(ss[nf][2]) | ((u32)f2bf(ss[nf][3]) << 16);
    }
  }
  __syncthreads();
  f32x4 o[4];
#pragma unroll
  for (int nf = 0; nf < 4; ++nf)
#pragma unroll
    for (int e = 0; e < 4; ++e) o[nf][e] = 0.f;
#pragma unroll
  for (int ks = 0; ks < 2; ++ks) {
    int cb = ks * 32 + g * 8;
    bf16x8 aA = ldsfrag(&A1[swA(row0 + r, cb)]);
    bf16x8 aV = ldsfrag(&LV[swA(row0 + r, cb)]);
#pragma unroll
    for (int nf = 0; nf < 4; ++nf) {
      bf16x8 bVT = ldsfrag(&LVT[swA(nf * 16 + r, cb)]);
      bf16x8 bA2 = ldsfrag(&A2[swA(nf * 16 + r, cb)]);
      o[nf] = __builtin_amdgcn_mfma_f32_16x16x32_bf16(aA, bVT, o[nf], 0, 0, 0);
      o[nf] = __builtin_amdgcn_mfma_f32_16x16x32_bf16(aV, bA2, o[nf], 0, 0, 0);
    }
  }
#pragma unroll
  for (int nf = 0; nf < 4; ++nf) {
    int vv = nf * 16 + r;
#pragma unroll
    for (int jj = 0; jj < 4; ++jj) {
      int u = row0 + g * 4 + jj;
      dst[base + (size_t)u * uStride + vv] = f2bf(o[nf][jj] * 0.5f);
    }
  }
}

// ---------------- final conv3d (cin=192 cat, cout=64) + BN + ReLU + BN + residual q ----------------
// 9 phases (3dh x 3t), per-tensor 64-ch pitch-72 register staging.
// K-loop: runtime dw outer, unrolled dd/c32 6-body with INLINE addresses (no P-table).
__global__ __launch_bounds__(512, 2) void conv_final(const u16* __restrict__ AVa,
    const u16* __restrict__ AVb, const u16* __restrict__ AVc, const u16* __restrict__ BCw,
    const float* __restrict__ bcb, const u16* __restrict__ qb, float* __restrict__ out) {
  __shared__ __align__(16) u16 xT[6 * 66 * 72];  // [wwi 0..5][dpos 0..65][cin64 swizzled]
  int tid = threadIdx.x;
  int id = blockIdx.x;
  int lin = (id & 7) * 256 + (id >> 3);  // 2048 = 8*256
  int b = lin >> 10, h = (lin >> 4) & 63, w0 = (lin & 15) * 4;
  int wave = tid >> 6, lane = tid & 63, r = lane & 15, g = lane >> 4;
  int mw = wave >> 1, nw = wave & 1;
  int pairid = tid >> 3, seg = tid & 7;
  if (tid < 384) {  // zero d-pad rows (dpos 0 and 65); swizzle identity there
    int wwi = tid >> 6, ci = tid & 63;
    xT[(wwi * 66 + 0) * 72 + ci] = 0;
    xT[(wwi * 66 + 65) * 72 + ci] = 0;
  }
  f32x4 acc[4][2];
#pragma unroll
  for (int i = 0; i < 4; ++i)
#pragma unroll
    for (int j = 0; j < 2; ++j)
#pragma unroll
      for (int e = 0; e < 4; ++e) acc[i][j][e] = 0.f;

  for (int dh = 0; dh < 3; ++dh) {
    int hh = h + dh - 1;
    if ((unsigned)hh >= 64u) continue;
    for (int t = 0; t < 3; ++t) {
      const u16* sp = (t == 0) ? AVa : ((t == 1) ? AVb : AVc);
      __syncthreads();
#pragma unroll
      for (int pi = 0; pi < 3; ++pi) {
        int pair = pairid + 64 * pi;  // [0,192): wwi(6) x cin-pair(32)
        int wwi = pair >> 5, cin0 = (pair & 31) * 2;
        int ww = w0 + wwi - 1;
        uint4 ra{}, rb{};
        if ((unsigned)ww < 64u) {
          const u16* p = sp + (size_t)(b * 64 + cin0) * VOL + hh * 4096 + ww * 64 + seg * 8;
          ra = *(const uint4*)p;
          rb = *(const uint4*)(p + VOL);
        }
        union { uint4 vv; u16 ss[8]; } Ua, Ub;
        Ua.vv = ra; Ub.vv = rb;
        int rowb = wwi * 66;
#pragma unroll
        for (int di = 0; di < 8; ++di) {
          int dpos = seg * 8 + di + 1;
          *(u32*)&xT[(rowb + dpos) * 72 + (cin0 ^ (((dpos >> 3) & 7) << 3))] =
              (u32)Ua.ss[di] | ((u32)Ub.ss[di] << 16);
        }
      }
      __syncthreads();
      const u16* Bp = BCw + ((size_t)((dh * 3 + t) * 18) * 4 + nw * 2) * 512 + (size_t)lane * 8;
      for (int dw = 0; dw < 3; ++dw) {
        int wwiE = (mw + dw) * 4752;  // 66*72
#pragma unroll
        for (int dd = 0; dd < 3; ++dd) {
#pragma unroll
          for (int c32 = 0; c32 < 2; ++c32) {
            int colb = c32 * 32 + g * 8;
            bf16x8 A[4];
#pragma unroll
            for (int dq = 0; dq < 4; ++dq) {
              int dpos = dq * 16 + r + dd;
              A[dq] = ldsfrag(&xT[wwiE + dpos * 72 + (colb ^ (((dpos >> 3) & 7) << 3))]);
            }
#pragma unroll
            for (int nf = 0; nf < 2; ++nf) {
              bf16x8 Bf = *(const bf16x8*)(Bp + nf * 512);
#pragma unroll
              for (int dq = 0; dq < 4; ++dq)
                acc[dq][nf] = __builtin_amdgcn_mfma_f32_16x16x32_bf16(A[dq], Bf, acc[dq][nf], 0, 0, 0);
            }
            Bp += 4 * 512;  // next k-step (c32 fastest, then dd, then dw)
          }
        }
      }
    }
  }
  const float S = 0.9999950000374997f;  // 1/sqrt(1+1e-5)
#pragma unroll
  for (int nf = 0; nf < 2; ++nf) {
    int cout = (nw * 2 + nf) * 16 + r;
    float bsv = bcb[cout];
#pragma unroll
    for (int dq = 0; dq < 4; ++dq) {
      int d0 = dq * 16 + g * 4;
      int idx = (b * 64 + cout) * VOL + h * 4096 + (w0 + mw) * 64 + d0;
      u16x4 qv = *(const u16x4*)(qb + idx);
      float4 ov;
      float t0 = (acc[dq][nf][0] + bsv) * S; t0 = t0 > 0.f ? t0 : 0.f; ov.x = t0 * S + bf2f(qv[0]);
      float t1 = (acc[dq][nf][1] + bsv) * S; t1 = t1 > 0.f ? t1 : 0.f; ov.y = t1 * S + bf2f(qv[1]);
      float t2 = (acc[dq][nf][2] + bsv) * S; t2 = t2 > 0.f ? t2 : 0.f; ov.z = t2 * S + bf2f(qv[2]);
      float t3 = (acc[dq][nf][3] + bsv) * S; t3 = t3 > 0.f ? t3 : 0.f; ov.w = t3 * S + bf2f(qv[3]);
      *(float4*)(out + idx) = ov;
    }
  }
}

extern "C" void kernel_launch(void* const* d_in, const int* in_sizes, int n_in,
                              void* d_out, int out_size, void* d_ws, size_t ws_size,
                              hipStream_t stream) {
  const float* x  = (const float*)d_in[0];
  const float* Wq = (const float*)d_in[1];
  const float* bq = (const float*)d_in[2];
  const float* Wk = (const float*)d_in[3];
  const float* bk = (const float*)d_in[4];
  const float* Wv = (const float*)d_in[5];
  const float* bv = (const float*)d_in[6];
  const float* Wc = (const float*)d_in[7];
  const float* bc = (const float*)d_in[8];
  float* out = (float*)d_out;
  u16* ws = (u16*)d_ws;
  const size_t T = (size_t)33554432;
  u16* qb = ws;
  u16* kb = ws + T;
  u16* vb = ws + 2 * T;
  u16* qT = ws + 3 * T;
  u16* kT = ws + 4 * T;
  u16* vT = ws + 5 * T;
  u16* xcl = ws + 6 * T;   // channels-last bf16 x; dead after conv_qkv
  u16* avaT = ws + 6 * T;  // pass-1 attn output overwrites xcl (stream-ordered)
  u16* BQ = ws + 7 * T;
  u16* BC = BQ + 331776;
  u16* AVa = qT;  // aliases: qT/kT/vT dead after attn pass 1
  u16* AVb = kT;
  u16* AVc = vT;

  swz_qkv<<<1296, 256, 0, stream>>>(Wq, Wk, Wv, BQ);
  swz_c<<<1296, 256, 0, stream>>>(Wc, BC);
  xcvt<<<8192, 256, 0, stream>>>(x, xcl);
  conv_qkv<<<4096, 512, 0, stream>>>(xcl, BQ, bq, bk, bv, qb, kb, vb);
  ktranspose<<<8192, 256, 0, stream>>>(qb, qT, 4096, 64);
  ktranspose<<<8192, 256, 0, stream>>>(kb, kT, 4096, 64);
  ktranspose<<<8192, 256, 0, stream>>>(vb, vT, 4096, 64);
  attn_pair<<<8192, 256, 0, stream>>>(qT, kT, vT, avaT, 64, 4096);
  ktranspose<<<8192, 256, 0, stream>>>(avaT, AVa, 64, 4096);
  attn_pair<<<8192, 256, 0, stream>>>(qb, kb, vb, AVb, 4096, 64);
  attn_pair<<<8192, 256, 0, stream>>>(qb, kb, vb, AVc, 64, 4096);
  conv_final<<<2048, 512, 0, stream>>>(AVa, AVb, AVc, BC, bc, qb, out);
}

// Round 11
// 1015.931 us; speedup vs baseline: 1.1661x; 1.0968x over previous
//
#include <hip/hip_runtime.h>

typedef unsigned short u16;
typedef unsigned int u32;
typedef __attribute__((ext_vector_type(8))) __bf16 bf16x8;
typedef __attribute__((ext_vector_type(4))) float f32x4;
typedef __attribute__((ext_vector_type(4))) u16 u16x4;

#define VOL 262144  // 64^3

__device__ __forceinline__ u16 f2bf(float f) {
  u32 u = __builtin_bit_cast(u32, f);
  u32 r = u + 0x7FFFu + ((u >> 16) & 1u);
  return (u16)(r >> 16);
}
__device__ __forceinline__ float bf2f(u16 h) {
  return __builtin_bit_cast(float, ((u32)h) << 16);
}
__device__ __forceinline__ bf16x8 ldsfrag(const u16* p) { return *(const bf16x8*)p; }

// async 16B/lane global->LDS: LDS dest = uniform base + lane*16, global src per-lane.
__device__ __forceinline__ void gload16(const u16* g, u16* l) {
  __builtin_amdgcn_global_load_lds(
      (const __attribute__((address_space(1))) u32*)g,
      (__attribute__((address_space(3))) u32*)l, 16, 0, 0);
}

// pitch-64 XOR swizzle: key varies with row bits 0-2 XOR 3-5, so both seg-strided
// staging writes and r-strided fragment reads spread across banks (proven in attn + R11 algebra).
__device__ __forceinline__ int swA(int row, int col) {
  return row * 64 + (col ^ (((row ^ (row >> 3)) & 7) << 3));
}

// ---------------- weight pre-swizzle: Wq/Wk/Wv -> per-lane B-fragment order ----------------
// K order (s in [0,54)): dh(3) / dw(3) / dd(3) / c32(2).  nf in [0,12): cout group of 16.
__global__ __launch_bounds__(256) void swz_qkv(const float* __restrict__ Wq,
    const float* __restrict__ Wk, const float* __restrict__ Wv, u16* __restrict__ out) {
  int idx = blockIdx.x * 256 + threadIdx.x;
  if (idx >= 54 * 12 * 64 * 8) return;
  int jj = idx & 7;
  int lane = (idx >> 3) & 63;
  int t = idx >> 9;
  int nf = t % 12, s = t / 12;
  int dh = s / 18, sub = s % 18;
  int dw = sub / 6, dd = (sub >> 1) % 3, c32 = sub & 1;
  int coutg = nf * 16 + (lane & 15);
  int cin = c32 * 32 + (lane >> 4) * 8 + jj;
  const float* W = (coutg < 64) ? Wq : ((coutg < 128) ? Wk : Wv);
  int c = coutg & 63;
  out[idx] = f2bf(W[(c * 64 + cin) * 27 + dh * 9 + dw * 3 + dd]);
}

// K order (s in [0,162)): dh(3) / t(3: AVa,AVb,AVc 64-ch block) / dw(3) / dd(3) / c32(2)
__global__ __launch_bounds__(256) void swz_c(const float* __restrict__ Wc, u16* __restrict__ out) {
  int idx = blockIdx.x * 256 + threadIdx.x;
  if (idx >= 162 * 4 * 64 * 8) return;
  int jj = idx & 7;
  int lane = (idx >> 3) & 63;
  int nf = (idx >> 9) & 3;
  int s = idx >> 11;
  int dh = s / 54, rem = s % 54;
  int t = rem / 18, sub = rem % 18;
  int dw = sub / 6, dd = (sub >> 1) % 3, c32 = sub & 1;
  int cout = nf * 16 + (lane & 15);
  int cin = t * 64 + c32 * 32 + (lane >> 4) * 8 + jj;
  out[idx] = f2bf(Wc[(cout * 192 + cin) * 27 + dh * 9 + dw * 3 + dd]);
}

// ---------------- x f32 [B,C,H,W,D] -> bf16 channels-last pre-swizzled [B,H,W][d][c^((d&7)<<3)] ----------------
__global__ __launch_bounds__(256, 4) void xcvt(const float* __restrict__ x, u16* __restrict__ xcl) {
  __shared__ __align__(16) u16 tile[4096];
  int id = blockIdx.x;  // (b*64+h)*64 + w
  int b = id >> 12;
  int t = threadIdx.x;
  int c0 = (t & 31) * 2, d0 = (t >> 5) * 8;
  const float* p0 = x + (size_t)(b * 64 + c0) * VOL + (size_t)(id & 4095) * 64 + d0;
  float4 r00 = *(const float4*)p0;
  float4 r01 = *(const float4*)(p0 + 4);
  float4 r10 = *(const float4*)(p0 + VOL);
  float4 r11 = *(const float4*)(p0 + VOL + 4);
  float a0[8] = {r00.x, r00.y, r00.z, r00.w, r01.x, r01.y, r01.z, r01.w};
  float a1[8] = {r10.x, r10.y, r10.z, r10.w, r11.x, r11.y, r11.z, r11.w};
#pragma unroll
  for (int i = 0; i < 8; ++i) {
    int d = d0 + i;
    *(u32*)&tile[d * 64 + (c0 ^ ((d & 7) << 3))] =
        (u32)f2bf(a0[i]) | ((u32)f2bf(a1[i]) << 16);
  }
  __syncthreads();
  u16* dst = xcl + ((size_t)id << 12);
  *(uint4*)&dst[t * 16] = *(const uint4*)&tile[t * 16];
  *(uint4*)&dst[t * 16 + 8] = *(const uint4*)&tile[t * 16 + 8];
}

// ---------------- fused q/k/v conv3d (implicit GEMM, BM=128, N=192, 8 waves, gload staging) ----------------
__global__ __launch_bounds__(512, 2) void conv_qkv(const u16* __restrict__ xcl,
    const u16* __restrict__ BQ, const float* __restrict__ bq, const float* __restrict__ bk,
    const float* __restrict__ bv, u16* __restrict__ qb, u16* __restrict__ kb,
    u16* __restrict__ vb) {
  __shared__ __align__(16) u16 xT[2 * 16896];  // 2 buf x 4 tiles x 4224 elems
  int tid = threadIdx.x;
  int id = blockIdx.x;
  int lin = (id & 7) * 512 + (id >> 3);
  int b = lin >> 11, h = (lin >> 5) & 63, w0 = (lin & 31) * 2;
  int wave = tid >> 6, lane = tid & 63, r = lane & 15, g = lane >> 4;
  int mhalf = wave >> 2, nq = wave & 3;
  {
    int tl = tid >> 7, rs = (tid >> 6) & 1, ci = tid & 63;
    int off = tl * 4224 + rs * 65 * 64 + ci;
    xT[off] = 0;
    xT[16896 + off] = 0;
  }
  if (w0 == 0) {
    *(uint4*)&xT[64 + tid * 8] = uint4{0, 0, 0, 0};
    *(uint4*)&xT[16896 + 64 + tid * 8] = uint4{0, 0, 0, 0};
  }
  if (w0 == 62) {
    *(uint4*)&xT[3 * 4224 + 64 + tid * 8] = uint4{0, 0, 0, 0};
    *(uint4*)&xT[16896 + 3 * 4224 + 64 + tid * 8] = uint4{0, 0, 0, 0};
  }
  int tw = wave >> 1, half = wave & 1;
  int wws = w0 + tw - 1;
  bool doload = (unsigned)wws < 64u;

  f32x4 acc[4][3];
#pragma unroll
  for (int i = 0; i < 4; ++i)
#pragma unroll
    for (int j = 0; j < 3; ++j)
#pragma unroll
      for (int e = 0; e < 4; ++e) acc[i][j][e] = 0.0f;

  int dhlo = (h == 0) ? 1 : 0, dhhi = (h == 63) ? 1 : 2;
  if (doload) {
    int hh = h + dhlo - 1;
    const u16* gp = xcl + (((size_t)(b * 64 + hh) * 64 + wws) << 12) + (half << 11) + (lane << 3);
    u16* lp = &xT[tw * 4224 + 64 + half * 2048];
#pragma unroll
    for (int j = 0; j < 4; ++j) gload16(gp + j * 512, lp + j * 512);
  }
  int cur = 0;
  for (int dh = dhlo; dh <= dhhi; ++dh) {
    __syncthreads();
    if (dh < dhhi && doload) {
      int hh = h + dh;
      const u16* gp =
          xcl + (((size_t)(b * 64 + hh) * 64 + wws) << 12) + (half << 11) + (lane << 3);
      u16* lp = &xT[(cur ^ 1) * 16896 + tw * 4224 + 64 + half * 2048];
#pragma unroll
      for (int j = 0; j < 4; ++j) gload16(gp + j * 512, lp + j * 512);
    }
    const u16* Bbase = BQ + ((size_t)(dh * 18) * 12 + nq * 3) * 512 + (size_t)lane * 8;
    int bufE = cur * 16896;
    for (int sub = 0; sub < 18; ++sub) {
      int dw = sub / 6, dd = (sub >> 1) % 3, c32 = sub & 1;
      int colb = c32 * 32 + g * 8;
      int wwi = mhalf + dw;
      bf16x8 A[4];
#pragma unroll
      for (int l = 0; l < 4; ++l) {
        int dpos = l * 16 + r + dd;
        A[l] = ldsfrag(&xT[bufE + wwi * 4224 + dpos * 64 + (colb ^ (((dpos - 1) & 7) << 3))]);
      }
      const u16* Bp = Bbase + (size_t)sub * 12 * 512;
#pragma unroll
      for (int nf = 0; nf < 3; ++nf) {
        bf16x8 Bf = *(const bf16x8*)(Bp + nf * 512);
#pragma unroll
        for (int l = 0; l < 4; ++l)
          acc[l][nf] = __builtin_amdgcn_mfma_f32_16x16x32_bf16(A[l], Bf, acc[l][nf], 0, 0, 0);
      }
    }
    cur ^= 1;
  }
#pragma unroll
  for (int nf = 0; nf < 3; ++nf) {
    int coutg = (nq * 3 + nf) * 16 + r;
    int ten = coutg >> 6, c = coutg & 63;
    u16* dst = (ten == 0) ? qb : ((ten == 1) ? kb : vb);
    const float* bias = (ten == 0) ? bq : ((ten == 1) ? bk : bv);
    float bsv = bias[c];
#pragma unroll
    for (int l = 0; l < 4; ++l) {
      int d0 = l * 16 + g * 4;
      int idx = (b * 64 + c) * VOL + h * 4096 + (w0 + mhalf) * 64 + d0;
      u16x4 o;
#pragma unroll
      for (int jj = 0; jj < 4; ++jj) o[jj] = f2bf(acc[l][nf][jj] + bsv);
      *(u16x4*)(dst + idx) = o;
    }
  }
}

// ---------------- tiled transpose within each (b,c) volume: src[P][Q] -> dst[Q][P] ----------------
__global__ __launch_bounds__(256, 6) void ktranspose(const u16* __restrict__ src,
    u16* __restrict__ dst, int P, int Q) {
  __shared__ __align__(16) u16 tile[64 * 72];
  int tid = threadIdx.x;
  int id = blockIdx.x;
  int bc = id >> 6, t = id & 63;
  int qt = Q >> 6;
  int p0 = (t / qt) * 64, q0 = (t % qt) * 64;
  const u16* s = src + (size_t)bc * VOL;
  u16* d = dst + (size_t)bc * VOL;
#pragma unroll
  for (int it = 0; it < 2; ++it) {
    int c = tid + 256 * it;
    int i2 = c >> 3, sg = c & 7;
    *(uint4*)&tile[i2 * 72 + ((sg * 8) ^ (((i2 >> 3) & 7) << 3))] =
        *(const uint4*)&s[(size_t)(p0 + i2) * Q + q0 + sg * 8];
  }
  __syncthreads();
  int j = tid >> 2, ms = tid & 3;
  u16 vals[16];
#pragma unroll
  for (int ii = 0; ii < 16; ++ii) {
    int row = ms * 16 + ii;
    vals[ii] = tile[row * 72 + (j ^ (((row >> 3) & 7) << 3))];
  }
  uint4 o0, o1;
  o0.x = (u32)vals[0] | ((u32)vals[1] << 16);
  o0.y = (u32)vals[2] | ((u32)vals[3] << 16);
  o0.z = (u32)vals[4] | ((u32)vals[5] << 16);
  o0.w = (u32)vals[6] | ((u32)vals[7] << 16);
  o1.x = (u32)vals[8] | ((u32)vals[9] << 16);
  o1.y = (u32)vals[10] | ((u32)vals[11] << 16);
  o1.z = (u32)vals[12] | ((u32)vals[13] << 16);
  o1.w = (u32)vals[14] | ((u32)vals[15] << 16);
  size_t drow = (size_t)(q0 + j) * P + p0 + ms * 16;
  *(uint4*)&d[drow] = o0;
  *(uint4*)&d[drow + 8] = o1;
}

// ---------------- axial attention pass-pair on 64x64 slabs ----------------
__global__ __launch_bounds__(256, 2) void attn_pair(const u16* __restrict__ q,
    const u16* __restrict__ k, const u16* __restrict__ v, u16* __restrict__ dst,
    int uStride, int sMul) {
  __shared__ __align__(16) u16 sm[6 * 4096];
  u16* LQ = sm;             u16* LK = sm + 4096;      u16* LV = sm + 2 * 4096;
  u16* LQT = sm + 3 * 4096; u16* LKT = sm + 4 * 4096; u16* LVT = sm + 5 * 4096;
  u16* A1 = LK;
  u16* A2 = LKT;
  int tid = threadIdx.x;
  int id = blockIdx.x;
  int bc = id >> 6, sidx = id & 63;
  size_t base = (size_t)bc * VOL + (size_t)sidx * sMul;
  int wave = tid >> 6, lane = tid & 63, r = lane & 15, g = lane >> 4;
  int pairid = tid >> 3, seg = tid & 7;
  int u0 = pairid * 2;
  const u16* srcs[3] = {q, k, v};
  u16* Ln_[3] = {LQ, LK, LV};
  u16* Lt_[3] = {LQT, LKT, LVT};
#pragma unroll
  for (int t3 = 0; t3 < 3; ++t3) {
    const u16* p = srcs[t3] + base + (size_t)u0 * uStride + seg * 8;
    uint4 ra = *(const uint4*)p;
    uint4 rb = *(const uint4*)(p + uStride);
    *(uint4*)&Ln_[t3][swA(u0, seg * 8)] = ra;
    *(uint4*)&Ln_[t3][swA(u0 + 1, seg * 8)] = rb;
    union { uint4 vv; u16 ss[8]; } Ua, Ub;
    Ua.vv = ra; Ub.vv = rb;
#pragma unroll
    for (int vi = 0; vi < 8; ++vi) {
      int vvx = seg * 8 + vi;
      *(u32*)&Lt_[t3][swA(vvx, u0)] = (u32)Ua.ss[vi] | ((u32)Ub.ss[vi] << 16);
    }
  }
  __syncthreads();
  int row0 = wave * 16;
  f32x4 s1[4], s2[4];
#pragma unroll
  for (int nf = 0; nf < 4; ++nf)
#pragma unroll
    for (int e = 0; e < 4; ++e) { s1[nf][e] = 0.f; s2[nf][e] = 0.f; }
#pragma unroll
  for (int ks = 0; ks < 2; ++ks) {
    int cb = ks * 32 + g * 8;
    bf16x8 aK = ldsfrag(&LK[swA(row0 + r, cb)]);
    bf16x8 aKT = ldsfrag(&LKT[swA(row0 + r, cb)]);
#pragma unroll
    for (int nf = 0; nf < 4; ++nf) {
      bf16x8 bQ = ldsfrag(&LQ[swA(nf * 16 + r, cb)]);
      bf16x8 bQT = ldsfrag(&LQT[swA(nf * 16 + r, cb)]);
      s1[nf] = __builtin_amdgcn_mfma_f32_16x16x32_bf16(aK, bQ, s1[nf], 0, 0, 0);
      s2[nf] = __builtin_amdgcn_mfma_f32_16x16x32_bf16(aKT, bQT, s2[nf], 0, 0, 0);
    }
  }
  __syncthreads();
#pragma unroll
  for (int m2 = 0; m2 < 2; ++m2) {
    f32x4* ss = m2 ? s2 : s1;
    u16* Adst = m2 ? A2 : A1;
#pragma unroll
    for (int jj = 0; jj < 4; ++jj) {
      float mx = fmaxf(fmaxf(ss[0][jj], ss[1][jj]), fmaxf(ss[2][jj], ss[3][jj]));
      mx = fmaxf(mx, __shfl_xor(mx, 1, 64));
      mx = fmaxf(mx, __shfl_xor(mx, 2, 64));
      mx = fmaxf(mx, __shfl_xor(mx, 4, 64));
      mx = fmaxf(mx, __shfl_xor(mx, 8, 64));
      float p0 = __expf((ss[0][jj] - mx) * 0.125f);
      float p1 = __expf((ss[1][jj] - mx) * 0.125f);
      float p2 = __expf((ss[2][jj] - mx) * 0.125f);
      float p3 = __expf((ss[3][jj] - mx) * 0.125f);
      float sum = p0 + p1 + p2 + p3;
      sum += __shfl_xor(sum, 1, 64);
      sum += __shfl_xor(sum, 2, 64);
      sum += __shfl_xor(sum, 4, 64);
      sum += __shfl_xor(sum, 8, 64);
      float inv = 1.0f / sum;
      ss[0][jj] = p0 * inv; ss[1][jj] = p1 * inv; ss[2][jj] = p2 * inv; ss[3][jj] = p3 * inv;
    }
    int j0 = row0 + g * 4;
#pragma unroll
    for (int nf = 0; nf < 4; ++nf) {
      int i = nf * 16 + r;
      int a0 = swA(i, j0);
      *(u32*)&Adst[a0]     = (u32)f2bf(ss[nf][0]) | ((u32)f2bf(ss[nf][1]) << 16);
      *(u32*)&Adst[a0 + 2] = (u32)f2bf(ss[nf][2]) | ((u32)f2bf(ss[nf][3]) << 16);
    }
  }
  __syncthreads();
  f32x4 o[4];
#pragma unroll
  for (int nf = 0; nf < 4; ++nf)
#pragma unroll
    for (int e = 0; e < 4; ++e) o[nf][e] = 0.f;
#pragma unroll
  for (int ks = 0; ks < 2; ++ks) {
    int cb = ks * 32 + g * 8;
    bf16x8 aA = ldsfrag(&A1[swA(row0 + r, cb)]);
    bf16x8 aV = ldsfrag(&LV[swA(row0 + r, cb)]);
#pragma unroll
    for (int nf = 0; nf < 4; ++nf) {
      bf16x8 bVT = ldsfrag(&LVT[swA(nf * 16 + r, cb)]);
      bf16x8 bA2 = ldsfrag(&A2[swA(nf * 16 + r, cb)]);
      o[nf] = __builtin_amdgcn_mfma_f32_16x16x32_bf16(aA, bVT, o[nf], 0, 0, 0);
      o[nf] = __builtin_amdgcn_mfma_f32_16x16x32_bf16(aV, bA2, o[nf], 0, 0, 0);
    }
  }
#pragma unroll
  for (int nf = 0; nf < 4; ++nf) {
    int vv = nf * 16 + r;
#pragma unroll
    for (int jj = 0; jj < 4; ++jj) {
      int u = row0 + g * 4 + jj;
      dst[base + (size_t)u * uStride + vv] = f2bf(o[nf][jj] * 0.5f);
    }
  }
}

// ---------------- final conv3d (cin=192 cat, cout=64) + BN + ReLU + BN + residual q ----------------
// 9 phases (3dh x 3t), per-tensor 64-ch register staging into pitch-64 swA-swizzled tiles.
// K-loop: the proven runtime 18-step form (R4/R5/R9/R10 all showed restructures regress).
__global__ __launch_bounds__(512, 2) void conv_final(const u16* __restrict__ AVa,
    const u16* __restrict__ AVb, const u16* __restrict__ AVc, const u16* __restrict__ BCw,
    const float* __restrict__ bcb, const u16* __restrict__ qb, float* __restrict__ out) {
  __shared__ __align__(16) u16 xT[6 * 4224];  // [wwi 0..5][dpos 0..65][cin64 swA-swizzled]
  int tid = threadIdx.x;
  int id = blockIdx.x;
  int lin = (id & 7) * 256 + (id >> 3);  // 2048 = 8*256
  int b = lin >> 10, h = (lin >> 4) & 63, w0 = (lin & 15) * 4;
  int wave = tid >> 6, lane = tid & 63, r = lane & 15, g = lane >> 4;
  int mw = wave >> 1, nw = wave & 1;
  int pairid = tid >> 3, seg = tid & 7;
  for (int z = tid; z < 768; z += 512) {  // zero pad rows (dpos 0 and 65) of 6 tiles
    int tl = z >> 7, rs = (z >> 6) & 1, ci = z & 63;
    xT[tl * 4224 + rs * 65 * 64 + ci] = 0;  // full row zeroed; swizzle is a col permutation
  }
  f32x4 acc[4][2];
#pragma unroll
  for (int i = 0; i < 4; ++i)
#pragma unroll
    for (int j = 0; j < 2; ++j)
#pragma unroll
      for (int e = 0; e < 4; ++e) acc[i][j][e] = 0.f;

  for (int dh = 0; dh < 3; ++dh) {
    int hh = h + dh - 1;
    if ((unsigned)hh >= 64u) continue;
    for (int t = 0; t < 3; ++t) {
      const u16* sp = (t == 0) ? AVa : ((t == 1) ? AVb : AVc);
      __syncthreads();
#pragma unroll
      for (int pi = 0; pi < 3; ++pi) {
        int pair = pairid + 64 * pi;  // [0,192): wwi(6) x cin-pair(32)
        int wwi = pair >> 5, cin0 = (pair & 31) * 2;
        int ww = w0 + wwi - 1;
        uint4 ra{}, rb{};
        if ((unsigned)ww < 64u) {
          const u16* p = sp + (size_t)(b * 64 + cin0) * VOL + hh * 4096 + ww * 64 + seg * 8;
          ra = *(const uint4*)p;
          rb = *(const uint4*)(p + VOL);
        }
        union { uint4 vv; u16 ss[8]; } Ua, Ub;
        Ua.vv = ra; Ub.vv = rb;
        int tE = wwi * 4224;
#pragma unroll
        for (int di = 0; di < 8; ++di) {
          int dpos = seg * 8 + di + 1;
          *(u32*)&xT[tE + swA(dpos, cin0)] = (u32)Ua.ss[di] | ((u32)Ub.ss[di] << 16);
        }
      }
      __syncthreads();
      for (int sub = 0; sub < 18; ++sub) {
        int dw = sub / 6, dd = (sub >> 1) % 3, c32 = sub & 1;
        int colb = c32 * 32 + g * 8;
        int wwiE = (mw + dw) * 4224;
        bf16x8 A[4];
#pragma unroll
        for (int dq = 0; dq < 4; ++dq) {
          int dpos = dq * 16 + r + dd;
          A[dq] = ldsfrag(&xT[wwiE + swA(dpos, colb)]);
        }
        const u16* Bp = BCw + ((size_t)(((dh * 3 + t) * 18 + sub) * 4 + nw * 2) * 64 + lane) * 8;
#pragma unroll
        for (int nf = 0; nf < 2; ++nf) {
          bf16x8 Bf = *(const bf16x8*)(Bp + nf * 512);
#pragma unroll
          for (int dq = 0; dq < 4; ++dq)
            acc[dq][nf] = __builtin_amdgcn_mfma_f32_16x16x32_bf16(A[dq], Bf, acc[dq][nf], 0, 0, 0);
        }
      }
    }
  }
  const float S = 0.9999950000374997f;  // 1/sqrt(1+1e-5)
#pragma unroll
  for (int nf = 0; nf < 2; ++nf) {
    int cout = (nw * 2 + nf) * 16 + r;
    float bsv = bcb[cout];
#pragma unroll
    for (int dq = 0; dq < 4; ++dq) {
      int d0 = dq * 16 + g * 4;
      int idx = (b * 64 + cout) * VOL + h * 4096 + (w0 + mw) * 64 + d0;
      u16x4 qv = *(const u16x4*)(qb + idx);
      float4 ov;
      float t0 = (acc[dq][nf][0] + bsv) * S; t0 = t0 > 0.f ? t0 : 0.f; ov.x = t0 * S + bf2f(qv[0]);
      float t1 = (acc[dq][nf][1] + bsv) * S; t1 = t1 > 0.f ? t1 : 0.f; ov.y = t1 * S + bf2f(qv[1]);
      float t2 = (acc[dq][nf][2] + bsv) * S; t2 = t2 > 0.f ? t2 : 0.f; ov.z = t2 * S + bf2f(qv[2]);
      float t3 = (acc[dq][nf][3] + bsv) * S; t3 = t3 > 0.f ? t3 : 0.f; ov.w = t3 * S + bf2f(qv[3]);
      *(float4*)(out + idx) = ov;
    }
  }
}

extern "C" void kernel_launch(void* const* d_in, const int* in_sizes, int n_in,
                              void* d_out, int out_size, void* d_ws, size_t ws_size,
                              hipStream_t stream) {
  const float* x  = (const float*)d_in[0];
  const float* Wq = (const float*)d_in[1];
  const float* bq = (const float*)d_in[2];
  const float* Wk = (const float*)d_in[3];
  const float* bk = (const float*)d_in[4];
  const float* Wv = (const float*)d_in[5];
  const float* bv = (const float*)d_in[6];
  const float* Wc = (const float*)d_in[7];
  const float* bc = (const float*)d_in[8];
  float* out = (float*)d_out;
  u16* ws = (u16*)d_ws;
  const size_t T = (size_t)33554432;
  u16* qb = ws;
  u16* kb = ws + T;
  u16* vb = ws + 2 * T;
  u16* qT = ws + 3 * T;
  u16* kT = ws + 4 * T;
  u16* vT = ws + 5 * T;
  u16* xcl = ws + 6 * T;   // channels-last bf16 x; dead after conv_qkv
  u16* avaT = ws + 6 * T;  // pass-1 attn output overwrites xcl (stream-ordered)
  u16* BQ = ws + 7 * T;
  u16* BC = BQ + 331776;
  u16* AVa = qT;  // aliases: qT/kT/vT dead after attn pass 1
  u16* AVb = kT;
  u16* AVc = vT;

  swz_qkv<<<1296, 256, 0, stream>>>(Wq, Wk, Wv, BQ);
  swz_c<<<1296, 256, 0, stream>>>(Wc, BC);
  xcvt<<<8192, 256, 0, stream>>>(x, xcl);
  conv_qkv<<<4096, 512, 0, stream>>>(xcl, BQ, bq, bk, bv, qb, kb, vb);
  ktranspose<<<8192, 256, 0, stream>>>(qb, qT, 4096, 64);
  ktranspose<<<8192, 256, 0, stream>>>(kb, kT, 4096, 64);
  ktranspose<<<8192, 256, 0, stream>>>(vb, vT, 4096, 64);
  attn_pair<<<8192, 256, 0, stream>>>(qT, kT, vT, avaT, 64, 4096);
  ktranspose<<<8192, 256, 0, stream>>>(avaT, AVa, 64, 4096);
  attn_pair<<<8192, 256, 0, stream>>>(qb, kb, vb, AVb, 4096, 64);
  attn_pair<<<8192, 256, 0, stream>>>(qb, kb, vb, AVc, 64, 4096);
  conv_final<<<2048, 512, 0, stream>>>(AVa, AVb, AVc, BC, bc, qb, out);
}

// Round 12
// 995.848 us; speedup vs baseline: 1.1897x; 1.0202x over previous
//
#include <hip/hip_runtime.h>

typedef unsigned short u16;
typedef unsigned int u32;
typedef __attribute__((ext_vector_type(8))) __bf16 bf16x8;
typedef __attribute__((ext_vector_type(4))) float f32x4;
typedef __attribute__((ext_vector_type(4))) u16 u16x4;

#define VOL 262144  // 64^3

__device__ __forceinline__ u16 f2bf(float f) {
  u32 u = __builtin_bit_cast(u32, f);
  u32 r = u + 0x7FFFu + ((u >> 16) & 1u);
  return (u16)(r >> 16);
}
__device__ __forceinline__ float bf2f(u16 h) {
  return __builtin_bit_cast(float, ((u32)h) << 16);
}
__device__ __forceinline__ bf16x8 ldsfrag(const u16* p) { return *(const bf16x8*)p; }

// async 16B/lane global->LDS: LDS dest = uniform base + lane*16, global src per-lane.
__device__ __forceinline__ void gload16(const u16* g, u16* l) {
  __builtin_amdgcn_global_load_lds(
      (const __attribute__((address_space(1))) u32*)g,
      (__attribute__((address_space(3))) u32*)l, 16, 0, 0);
}

// pitch-64 XOR swizzle for attn buffers (proven in attn_pair).
__device__ __forceinline__ int swA(int row, int col) {
  return row * 64 + (col ^ (((row ^ (row >> 3)) & 7) << 3));
}

// ---------------- weight pre-swizzle: Wq/Wk/Wv -> per-lane B-fragment order ----------------
// K order (s in [0,54)): dh(3) / dw(3) / dd(3) / c32(2).  nf in [0,12): cout group of 16.
__global__ __launch_bounds__(256) void swz_qkv(const float* __restrict__ Wq,
    const float* __restrict__ Wk, const float* __restrict__ Wv, u16* __restrict__ out) {
  int idx = blockIdx.x * 256 + threadIdx.x;
  if (idx >= 54 * 12 * 64 * 8) return;
  int jj = idx & 7;
  int lane = (idx >> 3) & 63;
  int t = idx >> 9;
  int nf = t % 12, s = t / 12;
  int dh = s / 18, sub = s % 18;
  int dw = sub / 6, dd = (sub >> 1) % 3, c32 = sub & 1;
  int coutg = nf * 16 + (lane & 15);
  int cin = c32 * 32 + (lane >> 4) * 8 + jj;
  const float* W = (coutg < 64) ? Wq : ((coutg < 128) ? Wk : Wv);
  int c = coutg & 63;
  out[idx] = f2bf(W[(c * 64 + cin) * 27 + dh * 9 + dw * 3 + dd]);
}

// K order (s in [0,162)): dh(3) / t(3: AVa,AVb,AVc 64-ch block) / dw(3) / dd(3) / c32(2)
__global__ __launch_bounds__(256) void swz_c(const float* __restrict__ Wc, u16* __restrict__ out) {
  int idx = blockIdx.x * 256 + threadIdx.x;
  if (idx >= 162 * 4 * 64 * 8) return;
  int jj = idx & 7;
  int lane = (idx >> 3) & 63;
  int nf = (idx >> 9) & 3;
  int s = idx >> 11;
  int dh = s / 54, rem = s % 54;
  int t = rem / 18, sub = rem % 18;
  int dw = sub / 6, dd = (sub >> 1) % 3, c32 = sub & 1;
  int cout = nf * 16 + (lane & 15);
  int cin = t * 64 + c32 * 32 + (lane >> 4) * 8 + jj;
  out[idx] = f2bf(Wc[(cout * 192 + cin) * 27 + dh * 9 + dw * 3 + dd]);
}

// ---------------- x f32 [B,C,H,W,D] -> bf16 channels-last pre-swizzled [B,H,W][d][c^((d&7)<<3)] ----------------
// Pitch-66 tile (odd word pitch): bank = d + colword mod 32 -> 2-way max on the output read.
__global__ __launch_bounds__(256, 4) void xcvt(const float* __restrict__ x, u16* __restrict__ xcl) {
  __shared__ __align__(16) u16 tile[64 * 66];
  int id = blockIdx.x;  // (b*64+h)*64 + w
  int b = id >> 12;
  int t = threadIdx.x;
  int c0 = (t & 31) * 2, d0 = (t >> 5) * 8;
  const float* p0 = x + (size_t)(b * 64 + c0) * VOL + (size_t)(id & 4095) * 64 + d0;
  float4 r00 = *(const float4*)p0;
  float4 r01 = *(const float4*)(p0 + 4);
  float4 r10 = *(const float4*)(p0 + VOL);
  float4 r11 = *(const float4*)(p0 + VOL + 4);
  float a0[8] = {r00.x, r00.y, r00.z, r00.w, r01.x, r01.y, r01.z, r01.w};
  float a1[8] = {r10.x, r10.y, r10.z, r10.w, r11.x, r11.y, r11.z, r11.w};
#pragma unroll
  for (int i = 0; i < 8; ++i) {
    int d = d0 + i;
    *(u32*)&tile[d * 66 + (c0 ^ ((d & 7) << 3))] =
        (u32)f2bf(a0[i]) | ((u32)f2bf(a1[i]) << 16);
  }
  __syncthreads();
  int dd = t >> 2, qq = t & 3;
  u16* dst = xcl + ((size_t)id << 12);
  *(uint4*)&dst[dd * 64 + qq * 16]     = *(const uint4*)&tile[dd * 66 + qq * 16];
  *(uint4*)&dst[dd * 64 + qq * 16 + 8] = *(const uint4*)&tile[dd * 66 + qq * 16 + 8];
}

// ---------------- fused q/k/v conv3d (implicit GEMM, BM=128, N=192, 8 waves, gload staging) ----------------
__global__ __launch_bounds__(512, 2) void conv_qkv(const u16* __restrict__ xcl,
    const u16* __restrict__ BQ, const float* __restrict__ bq, const float* __restrict__ bk,
    const float* __restrict__ bv, u16* __restrict__ qb, u16* __restrict__ kb,
    u16* __restrict__ vb) {
  __shared__ __align__(16) u16 xT[2 * 16896];  // 2 buf x 4 tiles x 4224 elems
  int tid = threadIdx.x;
  int id = blockIdx.x;
  int lin = (id & 7) * 512 + (id >> 3);
  int b = lin >> 11, h = (lin >> 5) & 63, w0 = (lin & 31) * 2;
  int wave = tid >> 6, lane = tid & 63, r = lane & 15, g = lane >> 4;
  int mhalf = wave >> 2, nq = wave & 3;
  {
    int tl = tid >> 7, rs = (tid >> 6) & 1, ci = tid & 63;
    int off = tl * 4224 + rs * 65 * 64 + ci;
    xT[off] = 0;
    xT[16896 + off] = 0;
  }
  if (w0 == 0) {
    *(uint4*)&xT[64 + tid * 8] = uint4{0, 0, 0, 0};
    *(uint4*)&xT[16896 + 64 + tid * 8] = uint4{0, 0, 0, 0};
  }
  if (w0 == 62) {
    *(uint4*)&xT[3 * 4224 + 64 + tid * 8] = uint4{0, 0, 0, 0};
    *(uint4*)&xT[16896 + 3 * 4224 + 64 + tid * 8] = uint4{0, 0, 0, 0};
  }
  int tw = wave >> 1, half = wave & 1;
  int wws = w0 + tw - 1;
  bool doload = (unsigned)wws < 64u;

  f32x4 acc[4][3];
#pragma unroll
  for (int i = 0; i < 4; ++i)
#pragma unroll
    for (int j = 0; j < 3; ++j)
#pragma unroll
      for (int e = 0; e < 4; ++e) acc[i][j][e] = 0.0f;

  int dhlo = (h == 0) ? 1 : 0, dhhi = (h == 63) ? 1 : 2;
  if (doload) {
    int hh = h + dhlo - 1;
    const u16* gp = xcl + (((size_t)(b * 64 + hh) * 64 + wws) << 12) + (half << 11) + (lane << 3);
    u16* lp = &xT[tw * 4224 + 64 + half * 2048];
#pragma unroll
    for (int j = 0; j < 4; ++j) gload16(gp + j * 512, lp + j * 512);
  }
  int cur = 0;
  for (int dh = dhlo; dh <= dhhi; ++dh) {
    __syncthreads();
    if (dh < dhhi && doload) {
      int hh = h + dh;
      const u16* gp =
          xcl + (((size_t)(b * 64 + hh) * 64 + wws) << 12) + (half << 11) + (lane << 3);
      u16* lp = &xT[(cur ^ 1) * 16896 + tw * 4224 + 64 + half * 2048];
#pragma unroll
      for (int j = 0; j < 4; ++j) gload16(gp + j * 512, lp + j * 512);
    }
    const u16* Bbase = BQ + ((size_t)(dh * 18) * 12 + nq * 3) * 512 + (size_t)lane * 8;
    int bufE = cur * 16896;
    for (int sub = 0; sub < 18; ++sub) {
      int dw = sub / 6, dd = (sub >> 1) % 3, c32 = sub & 1;
      int colb = c32 * 32 + g * 8;
      int wwi = mhalf + dw;
      bf16x8 A[4];
#pragma unroll
      for (int l = 0; l < 4; ++l) {
        int dpos = l * 16 + r + dd;
        A[l] = ldsfrag(&xT[bufE + wwi * 4224 + dpos * 64 + (colb ^ (((dpos - 1) & 7) << 3))]);
      }
      const u16* Bp = Bbase + (size_t)sub * 12 * 512;
#pragma unroll
      for (int nf = 0; nf < 3; ++nf) {
        bf16x8 Bf = *(const bf16x8*)(Bp + nf * 512);
#pragma unroll
        for (int l = 0; l < 4; ++l)
          acc[l][nf] = __builtin_amdgcn_mfma_f32_16x16x32_bf16(A[l], Bf, acc[l][nf], 0, 0, 0);
      }
    }
    cur ^= 1;
  }
#pragma unroll
  for (int nf = 0; nf < 3; ++nf) {
    int coutg = (nq * 3 + nf) * 16 + r;
    int ten = coutg >> 6, c = coutg & 63;
    u16* dst = (ten == 0) ? qb : ((ten == 1) ? kb : vb);
    const float* bias = (ten == 0) ? bq : ((ten == 1) ? bk : bv);
    float bsv = bias[c];
#pragma unroll
    for (int l = 0; l < 4; ++l) {
      int d0 = l * 16 + g * 4;
      int idx = (b * 64 + c) * VOL + h * 4096 + (w0 + mhalf) * 64 + d0;
      u16x4 o;
#pragma unroll
      for (int jj = 0; jj < 4; ++jj) o[jj] = f2bf(acc[l][nf][jj] + bsv);
      *(u16x4*)(dst + idx) = o;
    }
  }
}

// ---------------- merged transpose q/k/v: [b,c][h*w][d] -> [b,c][d][h*w] (pitch-66 tiles) ----------------
__global__ __launch_bounds__(256, 6) void ktranspose3(const u16* __restrict__ q,
    const u16* __restrict__ k, const u16* __restrict__ v, u16* __restrict__ qT,
    u16* __restrict__ kT, u16* __restrict__ vT) {
  __shared__ __align__(16) u16 tile[64 * 66];
  int id = blockIdx.x;
  int ten = id >> 13, rem = id & 8191;
  int bc = rem >> 6, t = rem & 63;
  const u16* s = ((ten == 0) ? q : (ten == 1) ? k : v) + (size_t)bc * VOL;
  u16* d = ((ten == 0) ? qT : (ten == 1) ? kT : vT) + (size_t)bc * VOL;
  int tid = threadIdx.x;
  int p0 = t * 64;  // P=4096 rows, Q=64 cols; q0=0
#pragma unroll
  for (int it = 0; it < 2; ++it) {
    int c = tid + 256 * it;
    int i2 = c >> 3, sg = c & 7;
    *(uint4*)&tile[i2 * 66 + sg * 8] = *(const uint4*)&s[(size_t)(p0 + i2) * 64 + sg * 8];
  }
  __syncthreads();
  int j = tid >> 2, ms = tid & 3;
  u16 vals[16];
#pragma unroll
  for (int ii = 0; ii < 16; ++ii) vals[ii] = tile[(ms * 16 + ii) * 66 + j];
  uint4 o0, o1;
  o0.x = (u32)vals[0] | ((u32)vals[1] << 16);
  o0.y = (u32)vals[2] | ((u32)vals[3] << 16);
  o0.z = (u32)vals[4] | ((u32)vals[5] << 16);
  o0.w = (u32)vals[6] | ((u32)vals[7] << 16);
  o1.x = (u32)vals[8] | ((u32)vals[9] << 16);
  o1.y = (u32)vals[10] | ((u32)vals[11] << 16);
  o1.z = (u32)vals[12] | ((u32)vals[13] << 16);
  o1.w = (u32)vals[14] | ((u32)vals[15] << 16);
  size_t drow = (size_t)j * 4096 + p0 + ms * 16;
  *(uint4*)&d[drow] = o0;
  *(uint4*)&d[drow + 8] = o1;
}

// ---------------- generic tiled transpose (used for avaT -> AVa): src[P][Q] -> dst[Q][P] ----------------
__global__ __launch_bounds__(256, 6) void ktranspose(const u16* __restrict__ src,
    u16* __restrict__ dst, int P, int Q) {
  __shared__ __align__(16) u16 tile[64 * 66];
  int tid = threadIdx.x;
  int id = blockIdx.x;
  int bc = id >> 6, t = id & 63;
  int qt = Q >> 6;
  int p0 = (t / qt) * 64, q0 = (t % qt) * 64;
  const u16* s = src + (size_t)bc * VOL;
  u16* d = dst + (size_t)bc * VOL;
#pragma unroll
  for (int it = 0; it < 2; ++it) {
    int c = tid + 256 * it;
    int i2 = c >> 3, sg = c & 7;
    *(uint4*)&tile[i2 * 66 + sg * 8] = *(const uint4*)&s[(size_t)(p0 + i2) * Q + q0 + sg * 8];
  }
  __syncthreads();
  int j = tid >> 2, ms = tid & 3;
  u16 vals[16];
#pragma unroll
  for (int ii = 0; ii < 16; ++ii) vals[ii] = tile[(ms * 16 + ii) * 66 + j];
  uint4 o0, o1;
  o0.x = (u32)vals[0] | ((u32)vals[1] << 16);
  o0.y = (u32)vals[2] | ((u32)vals[3] << 16);
  o0.z = (u32)vals[4] | ((u32)vals[5] << 16);
  o0.w = (u32)vals[6] | ((u32)vals[7] << 16);
  o1.x = (u32)vals[8] | ((u32)vals[9] << 16);
  o1.y = (u32)vals[10] | ((u32)vals[11] << 16);
  o1.z = (u32)vals[12] | ((u32)vals[13] << 16);
  o1.w = (u32)vals[14] | ((u32)vals[15] << 16);
  size_t drow = (size_t)(q0 + j) * P + p0 + ms * 16;
  *(uint4*)&d[drow] = o0;
  *(uint4*)&d[drow + 8] = o1;
}

// ---------------- axial attention pass-pair on 64x64 slabs ----------------
__global__ __launch_bounds__(256, 2) void attn_pair(const u16* __restrict__ q,
    const u16* __restrict__ k, const u16* __restrict__ v, u16* __restrict__ dst,
    int uStride, int sMul) {
  __shared__ __align__(16) u16 sm[6 * 4096];
  u16* LQ = sm;             u16* LK = sm + 4096;      u16* LV = sm + 2 * 4096;
  u16* LQT = sm + 3 * 4096; u16* LKT = sm + 4 * 4096; u16* LVT = sm + 5 * 4096;
  u16* A1 = LK;
  u16* A2 = LKT;
  int tid = threadIdx.x;
  int id = blockIdx.x;
  int bc = id >> 6, sidx = id & 63;
  size_t base = (size_t)bc * VOL + (size_t)sidx * sMul;
  int wave = tid >> 6, lane = tid & 63, r = lane & 15, g = lane >> 4;
  int pairid = tid >> 3, seg = tid & 7;
  int u0 = pairid * 2;
  const u16* srcs[3] = {q, k, v};
  u16* Ln_[3] = {LQ, LK, LV};
  u16* Lt_[3] = {LQT, LKT, LVT};
#pragma unroll
  for (int t3 = 0; t3 < 3; ++t3) {
    const u16* p = srcs[t3] + base + (size_t)u0 * uStride + seg * 8;
    uint4 ra = *(const uint4*)p;
    uint4 rb = *(const uint4*)(p + uStride);
    *(uint4*)&Ln_[t3][swA(u0, seg * 8)] = ra;
    *(uint4*)&Ln_[t3][swA(u0 + 1, seg * 8)] = rb;
    union { uint4 vv; u16 ss[8]; } Ua, Ub;
    Ua.vv = ra; Ub.vv = rb;
#pragma unroll
    for (int vi = 0; vi < 8; ++vi) {
      int vvx = seg * 8 + vi;
      *(u32*)&Lt_[t3][swA(vvx, u0)] = (u32)Ua.ss[vi] | ((u32)Ub.ss[vi] << 16);
    }
  }
  __syncthreads();
  int row0 = wave * 16;
  f32x4 s1[4], s2[4];
#pragma unroll
  for (int nf = 0; nf < 4; ++nf)
#pragma unroll
    for (int e = 0; e < 4; ++e) { s1[nf][e] = 0.f; s2[nf][e] = 0.f; }
#pragma unroll
  for (int ks = 0; ks < 2; ++ks) {
    int cb = ks * 32 + g * 8;
    bf16x8 aK = ldsfrag(&LK[swA(row0 + r, cb)]);
    bf16x8 aKT = ldsfrag(&LKT[swA(row0 + r, cb)]);
#pragma unroll
    for (int nf = 0; nf < 4; ++nf) {
      bf16x8 bQ = ldsfrag(&LQ[swA(nf * 16 + r, cb)]);
      bf16x8 bQT = ldsfrag(&LQT[swA(nf * 16 + r, cb)]);
      s1[nf] = __builtin_amdgcn_mfma_f32_16x16x32_bf16(aK, bQ, s1[nf], 0, 0, 0);
      s2[nf] = __builtin_amdgcn_mfma_f32_16x16x32_bf16(aKT, bQT, s2[nf], 0, 0, 0);
    }
  }
  __syncthreads();
#pragma unroll
  for (int m2 = 0; m2 < 2; ++m2) {
    f32x4* ss = m2 ? s2 : s1;
    u16* Adst = m2 ? A2 : A1;
#pragma unroll
    for (int jj = 0; jj < 4; ++jj) {
      float mx = fmaxf(fmaxf(ss[0][jj], ss[1][jj]), fmaxf(ss[2][jj], ss[3][jj]));
      mx = fmaxf(mx, __shfl_xor(mx, 1, 64));
      mx = fmaxf(mx, __shfl_xor(mx, 2, 64));
      mx = fmaxf(mx, __shfl_xor(mx, 4, 64));
      mx = fmaxf(mx, __shfl_xor(mx, 8, 64));
      float p0 = __expf((ss[0][jj] - mx) * 0.125f);
      float p1 = __expf((ss[1][jj] - mx) * 0.125f);
      float p2 = __expf((ss[2][jj] - mx) * 0.125f);
      float p3 = __expf((ss[3][jj] - mx) * 0.125f);
      float sum = p0 + p1 + p2 + p3;
      sum += __shfl_xor(sum, 1, 64);
      sum += __shfl_xor(sum, 2, 64);
      sum += __shfl_xor(sum, 4, 64);
      sum += __shfl_xor(sum, 8, 64);
      float inv = 1.0f / sum;
      ss[0][jj] = p0 * inv; ss[1][jj] = p1 * inv; ss[2][jj] = p2 * inv; ss[3][jj] = p3 * inv;
    }
    int j0 = row0 + g * 4;
#pragma unroll
    for (int nf = 0; nf < 4; ++nf) {
      int i = nf * 16 + r;
      int a0 = swA(i, j0);
      *(u32*)&Adst[a0]     = (u32)f2bf(ss[nf][0]) | ((u32)f2bf(ss[nf][1]) << 16);
      *(u32*)&Adst[a0 + 2] = (u32)f2bf(ss[nf][2]) | ((u32)f2bf(ss[nf][3]) << 16);
    }
  }
  __syncthreads();
  f32x4 o[4];
#pragma unroll
  for (int nf = 0; nf < 4; ++nf)
#pragma unroll
    for (int e = 0; e < 4; ++e) o[nf][e] = 0.f;
#pragma unroll
  for (int ks = 0; ks < 2; ++ks) {
    int cb = ks * 32 + g * 8;
    bf16x8 aA = ldsfrag(&A1[swA(row0 + r, cb)]);
    bf16x8 aV = ldsfrag(&LV[swA(row0 + r, cb)]);
#pragma unroll
    for (int nf = 0; nf < 4; ++nf) {
      bf16x8 bVT = ldsfrag(&LVT[swA(nf * 16 + r, cb)]);
      bf16x8 bA2 = ldsfrag(&A2[swA(nf * 16 + r, cb)]);
      o[nf] = __builtin_amdgcn_mfma_f32_16x16x32_bf16(aA, bVT, o[nf], 0, 0, 0);
      o[nf] = __builtin_amdgcn_mfma_f32_16x16x32_bf16(aV, bA2, o[nf], 0, 0, 0);
    }
  }
#pragma unroll
  for (int nf = 0; nf < 4; ++nf) {
    int vv = nf * 16 + r;
#pragma unroll
    for (int jj = 0; jj < 4; ++jj) {
      int u = row0 + g * 4 + jj;
      dst[base + (size_t)u * uStride + vv] = f2bf(o[nf][jj] * 0.5f);
    }
  }
}

// ---------------- final conv3d (cin=192 cat, cout=64) + BN + ReLU + BN + residual q ----------------
// R7-proven version: 9 phases (3dh x 3t), pitch-72 register staging, runtime 18-step k-loop.
__global__ __launch_bounds__(512, 2) void conv_final(const u16* __restrict__ AVa,
    const u16* __restrict__ AVb, const u16* __restrict__ AVc, const u16* __restrict__ BCw,
    const float* __restrict__ bcb, const u16* __restrict__ qb, float* __restrict__ out) {
  __shared__ __align__(16) u16 xT[6 * 66 * 72];  // [wwi 0..5][dpos 0..65][cin64 swizzled]
  int tid = threadIdx.x;
  int id = blockIdx.x;
  int lin = (id & 7) * 256 + (id >> 3);  // 2048 = 8*256
  int b = lin >> 10, h = (lin >> 4) & 63, w0 = (lin & 15) * 4;
  int wave = tid >> 6, lane = tid & 63, r = lane & 15, g = lane >> 4;
  int mw = wave >> 1, nw = wave & 1;
  int pairid = tid >> 3, seg = tid & 7;
  if (tid < 384) {  // zero d-pad rows (dpos 0 and 65); swizzle identity there
    int wwi = tid >> 6, ci = tid & 63;
    xT[(wwi * 66 + 0) * 72 + ci] = 0;
    xT[(wwi * 66 + 65) * 72 + ci] = 0;
  }
  f32x4 acc[4][2];
#pragma unroll
  for (int i = 0; i < 4; ++i)
#pragma unroll
    for (int j = 0; j < 2; ++j)
#pragma unroll
      for (int e = 0; e < 4; ++e) acc[i][j][e] = 0.f;

  for (int dh = 0; dh < 3; ++dh) {
    int hh = h + dh - 1;
    if ((unsigned)hh >= 64u) continue;
    for (int t = 0; t < 3; ++t) {
      const u16* sp = (t == 0) ? AVa : ((t == 1) ? AVb : AVc);
      __syncthreads();
#pragma unroll
      for (int pi = 0; pi < 3; ++pi) {
        int pair = pairid + 64 * pi;  // [0,192): wwi(6) x cin-pair(32)
        int wwi = pair >> 5, cin0 = (pair & 31) * 2;
        int ww = w0 + wwi - 1;
        uint4 ra{}, rb{};
        if ((unsigned)ww < 64u) {
          const u16* p = sp + (size_t)(b * 64 + cin0) * VOL + hh * 4096 + ww * 64 + seg * 8;
          ra = *(const uint4*)p;
          rb = *(const uint4*)(p + VOL);
        }
        union { uint4 vv; u16 ss[8]; } Ua, Ub;
        Ua.vv = ra; Ub.vv = rb;
        int rowb = wwi * 66;
#pragma unroll
        for (int di = 0; di < 8; ++di) {
          int dpos = seg * 8 + di + 1;
          *(u32*)&xT[(rowb + dpos) * 72 + (cin0 ^ (((dpos >> 3) & 7) << 3))] =
              (u32)Ua.ss[di] | ((u32)Ub.ss[di] << 16);
        }
      }
      __syncthreads();
      for (int sub = 0; sub < 18; ++sub) {
        int dw = sub / 6, dd = (sub >> 1) % 3, c32 = sub & 1;
        int colb = c32 * 32 + g * 8;
        int wwi = mw + dw;
        bf16x8 A[4];
#pragma unroll
        for (int dq = 0; dq < 4; ++dq) {
          int dpos = dq * 16 + r + dd;
          A[dq] = ldsfrag(&xT[(wwi * 66 + dpos) * 72 + (colb ^ (((dpos >> 3) & 7) << 3))]);
        }
        const u16* Bp = BCw + ((size_t)(((dh * 3 + t) * 18 + sub) * 4 + nw * 2) * 64 + lane) * 8;
#pragma unroll
        for (int nf = 0; nf < 2; ++nf) {
          bf16x8 Bf = *(const bf16x8*)(Bp + nf * 512);
#pragma unroll
          for (int dq = 0; dq < 4; ++dq)
            acc[dq][nf] = __builtin_amdgcn_mfma_f32_16x16x32_bf16(A[dq], Bf, acc[dq][nf], 0, 0, 0);
        }
      }
    }
  }
  const float S = 0.9999950000374997f;  // 1/sqrt(1+1e-5)
#pragma unroll
  for (int nf = 0; nf < 2; ++nf) {
    int cout = (nw * 2 + nf) * 16 + r;
    float bsv = bcb[cout];
#pragma unroll
    for (int dq = 0; dq < 4; ++dq) {
      int d0 = dq * 16 + g * 4;
      int idx = (b * 64 + cout) * VOL + h * 4096 + (w0 + mw) * 64 + d0;
      u16x4 qv = *(const u16x4*)(qb + idx);
      float4 ov;
      float t0 = (acc[dq][nf][0] + bsv) * S; t0 = t0 > 0.f ? t0 : 0.f; ov.x = t0 * S + bf2f(qv[0]);
      float t1 = (acc[dq][nf][1] + bsv) * S; t1 = t1 > 0.f ? t1 : 0.f; ov.y = t1 * S + bf2f(qv[1]);
      float t2 = (acc[dq][nf][2] + bsv) * S; t2 = t2 > 0.f ? t2 : 0.f; ov.z = t2 * S + bf2f(qv[2]);
      float t3 = (acc[dq][nf][3] + bsv) * S; t3 = t3 > 0.f ? t3 : 0.f; ov.w = t3 * S + bf2f(qv[3]);
      *(float4*)(out + idx) = ov;
    }
  }
}

extern "C" void kernel_launch(void* const* d_in, const int* in_sizes, int n_in,
                              void* d_out, int out_size, void* d_ws, size_t ws_size,
                              hipStream_t stream) {
  const float* x  = (const float*)d_in[0];
  const float* Wq = (const float*)d_in[1];
  const float* bq = (const float*)d_in[2];
  const float* Wk = (const float*)d_in[3];
  const float* bk = (const float*)d_in[4];
  const float* Wv = (const float*)d_in[5];
  const float* bv = (const float*)d_in[6];
  const float* Wc = (const float*)d_in[7];
  const float* bc = (const float*)d_in[8];
  float* out = (float*)d_out;
  u16* ws = (u16*)d_ws;
  const size_t T = (size_t)33554432;
  u16* qb = ws;
  u16* kb = ws + T;
  u16* vb = ws + 2 * T;
  u16* qT = ws + 3 * T;
  u16* kT = ws + 4 * T;
  u16* vT = ws + 5 * T;
  u16* xcl = ws + 6 * T;   // channels-last bf16 x; dead after conv_qkv
  u16* avaT = ws + 6 * T;  // pass-1 attn output overwrites xcl (stream-ordered)
  u16* BQ = ws + 7 * T;
  u16* BC = BQ + 331776;
  u16* AVa = qT;  // aliases: qT/kT/vT dead after attn pass 1
  u16* AVb = kT;
  u16* AVc = vT;

  swz_qkv<<<1296, 256, 0, stream>>>(Wq, Wk, Wv, BQ);
  swz_c<<<1296, 256, 0, stream>>>(Wc, BC);
  xcvt<<<8192, 256, 0, stream>>>(x, xcl);
  conv_qkv<<<4096, 512, 0, stream>>>(xcl, BQ, bq, bk, bv, qb, kb, vb);
  ktranspose3<<<24576, 256, 0, stream>>>(qb, kb, vb, qT, kT, vT);
  attn_pair<<<8192, 256, 0, stream>>>(qT, kT, vT, avaT, 64, 4096);
  ktranspose<<<8192, 256, 0, stream>>>(avaT, AVa, 64, 4096);
  attn_pair<<<8192, 256, 0, stream>>>(qb, kb, vb, AVb, 4096, 64);
  attn_pair<<<8192, 256, 0, stream>>>(qb, kb, vb, AVc, 64, 4096);
  conv_final<<<2048, 512, 0, stream>>>(AVa, AVb, AVc, BC, bc, qb, out);
}